// Round 6
// baseline (938.462 us; speedup 1.0000x reference)
//
#include <hip/hip_runtime.h>
#include <hip/hip_bf16.h>
#include <math.h>

// Problem constants
#define B_ 8
#define Q_ 200
#define K_ 16384
#define D_ 256
#define H_ 8
#define DH_ 32
#define ALIGNK_ 96
#define CROSSK_ 1024
#define FF_ 1024
#define BQ_ (B_*Q_)     // 1600
#define BK_ (B_*K_)     // 131072

typedef unsigned short u16;
typedef short bf16x8 __attribute__((ext_vector_type(8)));
typedef float f32x4 __attribute__((ext_vector_type(4)));

__device__ __forceinline__ float b2f(u16 u){ return __uint_as_float(((unsigned)u)<<16); }
__device__ __forceinline__ u16 f2b(float f){
  unsigned x = __float_as_uint(f);
  unsigned r = x + 0x7FFFu + ((x>>16)&1u);   // round-to-nearest-even
  return (u16)(r>>16);
}
__device__ __forceinline__ unsigned p2u(float lo, float hi){
  return (unsigned)f2b(lo) | ((unsigned)f2b(hi)<<16);
}
__device__ __forceinline__ uint4 pk8(float4 a, float4 b){
  return make_uint4(p2u(a.x,a.y), p2u(a.z,a.w), p2u(b.x,b.y), p2u(b.z,b.w));
}
// order-preserving float->uint key (larger float => larger key)
__device__ __forceinline__ unsigned fkey(float f){ unsigned b=__float_as_uint(f); return (b&0x80000000u)? ~b : (b|0x80000000u); }
__device__ __forceinline__ float funkey(unsigned k){ unsigned b=(k&0x80000000u)? (k^0x80000000u) : ~k; return __uint_as_float(b); }
__device__ __forceinline__ float gelu_f(float x){ return 0.5f*x*(1.0f+erff(x*0.70710678118654752f)); }
__device__ __forceinline__ float sigmoid_f(float x){ return 1.0f/(1.0f+__expf(-x)); }

// ---------------------------------------------------------------------------
// General NT GEMM:  C[m,n] = sum_k A[m,k]*B[n,k]  (fp32 acc). A/B each either
// fp32 (converted to bf16 in registers) or bf16. Tile 64x64, BK=64, 4 waves.
// ---------------------------------------------------------------------------
struct GArgs {
  const void* A; const void* B; const float* bias;
  float* Cf; u16* Cb; unsigned* amax;
  const int* gather;
  long lda, ldb, ldc;
  long sA, sB, sC, sAmax, sGather;
  int M, N, K, act;
};

template<int AF32, int BF32>
__global__ __launch_bounds__(256) void gemm_bt(GArgs g)
{
  const int tid = threadIdx.x;
  const int bz = blockIdx.z;
  const int m0 = blockIdx.y*64, n0 = blockIdx.x*64;
  const int lane = tid & 63, wave = tid >> 6;
  const int wr = wave >> 1, wc = wave & 1;
  __shared__ __align__(16) u16 As[64][72];
  __shared__ __align__(16) u16 Bs[64][72];
  f32x4 acc[2][2] = {};

  const int lrow = tid>>2;
  const int lk = (tid&3)*16;
  int ar = m0 + lrow; if (ar > g.M-1) ar = g.M-1;
  if (g.gather) ar = g.gather[(long)bz*g.sGather + ar];
  int br = n0 + lrow; if (br > g.N-1) br = g.N-1;
  long aoff = (long)bz*g.sA + (long)ar*g.lda + lk;
  long boff = (long)bz*g.sB + (long)br*g.ldb + lk;

  const int nk = g.K >> 6;
  for (int kt=0; kt<nk; ++kt){
    uint4 wa0, wa1, wb0, wb1;
    if (AF32){
      const float* p = (const float*)g.A + aoff;
      float4 f0 = *(const float4*)(p+0);
      float4 f1 = *(const float4*)(p+4);
      float4 f2v= *(const float4*)(p+8);
      float4 f3 = *(const float4*)(p+12);
      wa0 = pk8(f0,f1); wa1 = pk8(f2v,f3);
    } else {
      const u16* p = (const u16*)g.A + aoff;
      wa0 = *(const uint4*)p; wa1 = *(const uint4*)(p+8);
    }
    if (BF32){
      const float* p = (const float*)g.B + boff;
      float4 f0 = *(const float4*)(p+0);
      float4 f1 = *(const float4*)(p+4);
      float4 f2v= *(const float4*)(p+8);
      float4 f3 = *(const float4*)(p+12);
      wb0 = pk8(f0,f1); wb1 = pk8(f2v,f3);
    } else {
      const u16* p = (const u16*)g.B + boff;
      wb0 = *(const uint4*)p; wb1 = *(const uint4*)(p+8);
    }
    aoff += 64; boff += 64;
    __syncthreads();
    *(uint4*)&As[lrow][lk]   = wa0; *(uint4*)&As[lrow][lk+8] = wa1;
    *(uint4*)&Bs[lrow][lk]   = wb0; *(uint4*)&Bs[lrow][lk+8] = wb1;
    __syncthreads();
    #pragma unroll
    for (int kk=0; kk<2; ++kk){
      const int ko = kk*32 + (lane>>4)*8;
      bf16x8 af0 = *(const bf16x8*)&As[wr*32      + (lane&15)][ko];
      bf16x8 af1 = *(const bf16x8*)&As[wr*32 + 16 + (lane&15)][ko];
      bf16x8 bf0 = *(const bf16x8*)&Bs[wc*32      + (lane&15)][ko];
      bf16x8 bf1 = *(const bf16x8*)&Bs[wc*32 + 16 + (lane&15)][ko];
      acc[0][0] = __builtin_amdgcn_mfma_f32_16x16x32_bf16(af0, bf0, acc[0][0], 0,0,0);
      acc[0][1] = __builtin_amdgcn_mfma_f32_16x16x32_bf16(af0, bf1, acc[0][1], 0,0,0);
      acc[1][0] = __builtin_amdgcn_mfma_f32_16x16x32_bf16(af1, bf0, acc[1][0], 0,0,0);
      acc[1][1] = __builtin_amdgcn_mfma_f32_16x16x32_bf16(af1, bf1, acc[1][1], 0,0,0);
    }
  }

  if (g.amax){
    #pragma unroll
    for (int j=0;j<2;j++){
      float mx = -3.0e38f;
      #pragma unroll
      for (int i=0;i<2;i++)
        #pragma unroll
        for (int r=0;r<4;r++) mx = fmaxf(mx, acc[i][j][r]);
      mx = fmaxf(mx, __shfl_xor(mx, 16));
      mx = fmaxf(mx, __shfl_xor(mx, 32));
      if ((lane>>4)==0){
        int n = n0 + wc*32 + j*16 + (lane&15);
        if (n < g.N) atomicMax(&g.amax[(long)bz*g.sAmax + n], fkey(mx));
      }
    }
    return;
  }

  #pragma unroll
  for (int i=0;i<2;i++)
  #pragma unroll
  for (int j=0;j<2;j++)
  #pragma unroll
  for (int r=0;r<4;r++){
    int m = m0 + wr*32 + i*16 + (lane>>4)*4 + r;   // C row = quad*4+reg
    int n = n0 + wc*32 + j*16 + (lane&15);          // C col = lane&15
    if (m < g.M && n < g.N){
      float v = acc[i][j][r];
      if (g.bias) v += g.bias[n];
      if (g.act==1) v = gelu_f(v);
      else if (g.act==2) v = sigmoid_f(v);
      long ci = (long)bz*g.sC + (long)m*g.ldc + n;
      if (g.Cf) g.Cf[ci] = v; else g.Cb[ci] = f2b(v);
    }
  }
}

// fp32 -> bf16 weight conversion (one-shot, 256x256 matrices)
__global__ void w2b_kernel(const float* w, u16* wb, int n)
{
  int i = (blockIdx.x*256 + threadIdx.x)*8;
  if (i < n){
    float4 a = *(const float4*)(w+i), b = *(const float4*)(w+i+4);
    *(uint4*)(wb+i) = pk8(a,b);
  }
}

// ---------------------------------------------------------------------------
// Fused projection + row-L2-normalize (v2, occupancy-focused).
// ---------------------------------------------------------------------------
template<int AF32>
__global__ __launch_bounds__(256) void proj_l2norm(
    const void* Ain, long lda, const u16* Wb, u16* outp, int R)
{
  __shared__ __align__(16) u16 As[64][72];
  __shared__ __align__(16) u16 Bs[64][72];
  const int tid = threadIdx.x;
  const int m0 = blockIdx.x*64;
  const int lane = tid & 63, wave = tid >> 6;
  f32x4 acc[4][4] = {};

  const int lrow = tid>>2, lk = (tid&3)*16;
  int ar = m0 + lrow; if (ar > R-1) ar = R-1;

  for (int kt=0; kt<4; ++kt){
    uint4 wa0, wa1;
    if (AF32){
      const float* p = (const float*)Ain + (long)ar*lda + kt*64 + lk;
      wa0 = pk8(*(const float4*)(p+0), *(const float4*)(p+4));
      wa1 = pk8(*(const float4*)(p+8), *(const float4*)(p+12));
    } else {
      const u16* p = (const u16*)Ain + (long)ar*lda + kt*64 + lk;
      wa0 = *(const uint4*)p; wa1 = *(const uint4*)(p+8);
    }
    #pragma unroll
    for (int nc=0; nc<4; ++nc){
      const u16* wp = Wb + (long)(nc*64 + lrow)*256 + kt*64 + lk;
      uint4 wb0 = *(const uint4*)wp;
      uint4 wb1 = *(const uint4*)(wp+8);
      __syncthreads();
      if (nc==0){ *(uint4*)&As[lrow][lk] = wa0; *(uint4*)&As[lrow][lk+8] = wa1; }
      *(uint4*)&Bs[lrow][lk] = wb0; *(uint4*)&Bs[lrow][lk+8] = wb1;
      __syncthreads();
      #pragma unroll
      for (int kk=0; kk<2; ++kk){
        const int ko = kk*32 + (lane>>4)*8;
        bf16x8 af = *(const bf16x8*)&As[wave*16 + (lane&15)][ko];
        #pragma unroll
        for (int j=0; j<4; j++){
          bf16x8 bfr = *(const bf16x8*)&Bs[j*16 + (lane&15)][ko];
          acc[nc][j] = __builtin_amdgcn_mfma_f32_16x16x32_bf16(af, bfr, acc[nc][j], 0,0,0);
        }
      }
    }
  }

  #pragma unroll
  for (int r=0;r<4;r++){
    float ssq = 0.f;
    #pragma unroll
    for (int nc=0;nc<4;nc++)
      #pragma unroll
      for (int j=0;j<4;j++) ssq += acc[nc][j][r]*acc[nc][j][r];
    ssq += __shfl_xor(ssq,1); ssq += __shfl_xor(ssq,2);
    ssq += __shfl_xor(ssq,4); ssq += __shfl_xor(ssq,8);
    float inv = 1.0f/fmaxf(sqrtf(ssq), 1e-6f);
    int row = m0 + wave*16 + (lane>>4)*4 + r;
    if (row < R){
      u16* op = outp + (long)row*256 + (lane&15);
      #pragma unroll
      for (int nc=0;nc<4;nc++)
        #pragma unroll
        for (int j=0;j<4;j++) op[nc*64 + j*16] = f2b(acc[nc][j][r]*inv);
    }
  }
}

// ---------------------------------------------------------------------------
// Exact top-RANK of a 16384-long row (bitwise rank-select + tie-break).
// ---------------------------------------------------------------------------
__global__ __launch_bounds__(256) void topk_kernel(const float* inF, const unsigned* inK,
    long in_stride, int RANK, float* out_val, int* out_idx)
{
  __shared__ int red[2][4];
  __shared__ int redt[4];
  __shared__ int poss;
  int row = blockIdx.x, tid = threadIdx.x;
  unsigned kr[64];
  if (inF){
    const float4* p = (const float4*)(inF + (long)row*in_stride);
    #pragma unroll
    for (int jj=0;jj<16;jj++){
      float4 v = p[tid + jj*256];
      kr[jj*4+0]=fkey(v.x); kr[jj*4+1]=fkey(v.y); kr[jj*4+2]=fkey(v.z); kr[jj*4+3]=fkey(v.w);
    }
  } else {
    const uint4* p = (const uint4*)(inK + (long)row*in_stride);
    #pragma unroll
    for (int jj=0;jj<16;jj++){
      uint4 v = p[tid + jj*256];
      kr[jj*4+0]=v.x; kr[jj*4+1]=v.y; kr[jj*4+2]=v.z; kr[jj*4+3]=v.w;
    }
  }
  if (tid==0) poss = 0;

  unsigned u = 0; bool exact = false; int pp = 0;
  for (int bit=31; bit>=0; --bit){
    unsigned cand = u | (1u<<bit);
    int c = 0;
    #pragma unroll
    for (int j=0;j<64;j++) c += (kr[j] >= cand) ? 1 : 0;
    #pragma unroll
    for (int off=32; off; off>>=1) c += __shfl_down(c, off);
    if ((tid&63)==0) red[pp][tid>>6] = c;
    __syncthreads();
    c = red[pp][0]+red[pp][1]+red[pp][2]+red[pp][3];
    pp ^= 1;
    if (c >= RANK){
      u = cand;
      if (c == RANK){ exact = true; break; }
    }
  }

  int t = 0;
  if (!exact){
    int cgt = 0;
    #pragma unroll
    for (int j=0;j<64;j++) cgt += (kr[j] > u) ? 1 : 0;
    #pragma unroll
    for (int off=32; off; off>>=1) cgt += __shfl_down(cgt, off);
    __syncthreads();
    if ((tid&63)==0) redt[tid>>6] = cgt;
    __syncthreads();
    cgt = redt[0]+redt[1]+redt[2]+redt[3];
    int Req = RANK - cgt;   // >=1 always
    for (int bit=13; bit>=0; --bit){
      int cand = t | (1<<bit);
      int c = 0;
      #pragma unroll
      for (int j=0;j<64;j++){
        int e = (tid<<2) + (j&3) + ((j>>2)<<10);
        c += (kr[j]==u && e < cand) ? 1 : 0;
      }
      #pragma unroll
      for (int off=32; off; off>>=1) c += __shfl_down(c, off);
      __syncthreads();
      if ((tid&63)==0) redt[tid>>6] = c;
      __syncthreads();
      c = redt[0]+redt[1]+redt[2]+redt[3];
      if (c < Req) t = cand;
    }
  }
  __syncthreads();
  #pragma unroll
  for (int j=0;j<64;j++){
    int e = (tid<<2) + (j&3) + ((j>>2)<<10);
    unsigned kk = kr[j];
    bool win = exact ? (kk >= u) : (kk > u || (kk == u && e <= t));
    if (win){
      int p2 = atomicAdd(&poss, 1);
      out_val[(long)row*RANK + p2] = funkey(kk);
      out_idx[(long)row*RANK + p2] = e;
    }
  }
}

// ---------------------------------------------------------------------------
// aligned[row,:] = softmax(vals96) . memory[b, idx96, :]   (memory fp32)
// ---------------------------------------------------------------------------
__global__ __launch_bounds__(256) void align_combine(const float* vals, const int* idx,
    const float* memory, float* alignedv)
{
  __shared__ float w[96];
  __shared__ int id[96];
  __shared__ float reds[2];
  int row = blockIdx.x, tid = threadIdx.x;
  int b = row / 200;
  if (tid < 96){ w[tid] = vals[(long)row*96 + tid]; id[tid] = idx[(long)row*96 + tid]; }
  __syncthreads();
  if (tid < 64){
    float a = w[tid];
    float bb2 = (tid < 32) ? w[64+tid] : -3e38f;
    float m = fmaxf(a, bb2);
    #pragma unroll
    for (int off=32; off; off>>=1) m = fmaxf(m, __shfl_xor(m, off));
    if (tid==0) reds[0] = m;
  }
  __syncthreads();
  float m = reds[0];
  if (tid < 96) w[tid] = __expf(w[tid]-m);
  __syncthreads();
  if (tid < 64){
    float a = w[tid] + ((tid<32)? w[64+tid] : 0.f);
    #pragma unroll
    for (int off=32; off; off>>=1) a += __shfl_xor(a, off);
    if (tid==0) reds[1] = a;
  }
  __syncthreads();
  float invs = 1.0f/reds[1];
  float acc = 0.f;
  const float* mb = memory + (long)b*K_*D_;
  for (int k=0;k<96;k++) acc += w[k] * mb[(long)id[k]*D_ + tid];
  alignedv[(long)row*256 + tid] = acc*invs;
}

__global__ void make_cat(const float* q, const float* alignedv, u16* cat)
{
  int row = blockIdx.x, tid = threadIdx.x;
  long i = (long)row*256 + tid;
  cat[(long)row*512 + tid]       = f2b(q[i]);
  cat[(long)row*512 + 256 + tid] = f2b(alignedv[i]);
}

__global__ void combine_gate(const float* q, const float* q_pos, const float* alignedv,
    const float* gate, float* qx, u16* qx_b, u16* qk_b)
{
  int row = blockIdx.x, tid = threadIdx.x;
  long i = (long)row*256 + tid;
  float v = q[i] + gate[i]*alignedv[i];
  qx[i] = v;
  qx_b[i] = f2b(v);
  qk_b[i] = f2b(v + q_pos[i]);
}

// ---------------------------------------------------------------------------
// t = x + y; LN over D=256 (biased var, eps 1e-5). Optional outputs.
// ---------------------------------------------------------------------------
__global__ __launch_bounds__(256) void add_ln(const float* x, const float* y,
    const float* g, const float* bb, const float* q_pos,
    float* out_f, u16* out_b, u16* out_pos_b)
{
  __shared__ float red[8];
  int row = blockIdx.x, tid = threadIdx.x;
  long i = (long)row*256 + tid;
  float t = fminf(fmaxf(x[i] + y[i], -1e6f), 1e6f);
  float s1 = t, s2 = t*t;
  #pragma unroll
  for (int off=32; off; off>>=1){ s1 += __shfl_down(s1,off); s2 += __shfl_down(s2,off); }
  if ((tid&63)==0){ red[(tid>>6)*2] = s1; red[(tid>>6)*2+1] = s2; }
  __syncthreads();
  s1 = red[0]+red[2]+red[4]+red[6];
  s2 = red[1]+red[3]+red[5]+red[7];
  float mu = s1 * (1.0f/256.0f);
  float var = fmaxf(s2 * (1.0f/256.0f) - mu*mu, 0.f);
  float rstd = rsqrtf(var + 1e-5f);
  float v = (t-mu)*rstd*g[tid] + bb[tid];
  if (out_f) out_f[i] = v;
  if (out_b) out_b[i] = f2b(v);
  if (out_pos_b) out_pos_b[i] = f2b(v + q_pos[i]);
}

__global__ void fill_u32(unsigned* p, unsigned val, int n)
{ int i = blockIdx.x*256 + threadIdx.x; if (i<n) p[i] = val; }

// ---------------------------------------------------------------------------
// Dense bias gather, layout [b][q][j]: biasTq[b,q,j] = cbias[b,q,kidx[b,j]].
// Reads scattered within one 64KB row; writes coalesced.
// ---------------------------------------------------------------------------
__global__ __launch_bounds__(256) void bias_gather2(const float* cbias, const int* kidx,
    float* biasTq)
{
  int qq = blockIdx.x, b = blockIdx.y;
  const float* src = cbias + ((long)b*200+qq)*(long)K_;
  float* dst = biasTq + ((long)b*200+qq)*CROSSK_;
  const int* kp = kidx + b*CROSSK_;
  for (int j=threadIdx.x; j<CROSSK_; j+=256) dst[j] = src[kp[j]];
}

// ---------------------------------------------------------------------------
// MFMA attention, 3-kernel pipeline (fullws path).
// qk_score: S[bh][q][j] = scale*(Qh . Kh^T) + bias, masked -inf for j>=Lk.
// Fragment layouts mirror gemm_bt (A/B rows read as bf16x8 [row][k];
// C: col=lane&15, row=(lane>>4)*4+reg — verified mapping).
// ---------------------------------------------------------------------------
__global__ __launch_bounds__(256) void qk_score(
    const u16* Qb, int q_stride, const u16* KVb, int kv_stride, int k_off,
    int Lk, int Jpad, const float* biasTq, float* S, float scale)
{
  __shared__ __align__(16) u16 Qs[64][40];
  __shared__ __align__(16) u16 Ks[64][40];
  const int bh = blockIdx.z, b = bh>>3, h = bh&7;
  const int q0 = blockIdx.y*64, j0 = blockIdx.x*64;
  const int tid = threadIdx.x, lane = tid&63, w = tid>>6;
  {
    int row = tid>>2, c8 = (tid&3)*8;
    int qr = q0+row; if (qr>199) qr=199;
    *(uint4*)&Qs[row][c8] = *(const uint4*)(Qb + (long)(b*200+qr)*q_stride + h*32 + c8);
    int j = j0+row;
    uint4 kv = make_uint4(0,0,0,0);
    if (j < Lk) kv = *(const uint4*)(KVb + (long)(b*Lk+j)*kv_stride + k_off + c8);
    *(uint4*)&Ks[row][c8] = kv;
  }
  __syncthreads();
  bf16x8 af = *(const bf16x8*)&Qs[w*16 + (lane&15)][(lane>>4)*8];
  f32x4 acc[4];
  #pragma unroll
  for (int jj=0;jj<4;jj++){
    f32x4 zz = {};
    bf16x8 bfr = *(const bf16x8*)&Ks[jj*16 + (lane&15)][(lane>>4)*8];
    acc[jj] = __builtin_amdgcn_mfma_f32_16x16x32_bf16(af, bfr, zz, 0,0,0);
  }
  #pragma unroll
  for (int jj=0;jj<4;jj++)
  #pragma unroll
  for (int r=0;r<4;r++){
    int q = q0 + w*16 + (lane>>4)*4 + r;
    int j = j0 + jj*16 + (lane&15);
    if (q < 200){
      float s = acc[jj][r]*scale;
      if (biasTq) s += biasTq[((long)(b*200+q))*Jpad + j];
      if (j >= Lk) s = -3e38f;
      S[((long)bh*200 + q)*Jpad + j] = s;
    }
  }
}

// Exact row softmax over width JP (compile-time), P written bf16 (normalized).
template<int JP>
__global__ __launch_bounds__(256) void softmax_p(const float* S, u16* P)
{
  __shared__ float red[8];
  const long base = (long)blockIdx.x * JP;
  const int tid = threadIdx.x;
  constexpr int PER = JP/256;
  float v[PER];
  float m = -3e38f;
  #pragma unroll
  for (int i=0;i<PER;i++){ v[i] = S[base + tid + i*256]; m = fmaxf(m, v[i]); }
  #pragma unroll
  for (int off=32; off; off>>=1) m = fmaxf(m, __shfl_xor(m, off));
  if ((tid&63)==0) red[tid>>6] = m;
  __syncthreads();
  m = fmaxf(fmaxf(red[0],red[1]), fmaxf(red[2],red[3]));
  float s = 0.f;
  #pragma unroll
  for (int i=0;i<PER;i++){ v[i] = __expf(v[i]-m); s += v[i]; }
  #pragma unroll
  for (int off=32; off; off>>=1) s += __shfl_xor(s, off);
  if ((tid&63)==0) red[4+(tid>>6)] = s;
  __syncthreads();
  s = red[4]+red[5]+red[6]+red[7];
  float inv = 1.0f/s;   // s >= 1 always (max element contributes exp(0)=1)
  #pragma unroll
  for (int i=0;i<PER;i++) P[base + tid + i*256] = f2b(v[i]*inv);
}

// O[b,q,h*32+d] = sum_j P[bh,q,j] * V[b,j,d].  V transposed into LDS per tile.
__global__ __launch_bounds__(256) void pv_kernel(
    const u16* P, int Jpad, const u16* KVb, int kv_stride, int v_off, int Lk,
    u16* outp)
{
  __shared__ __align__(16) u16 Vt[32][72];
  const int bh = blockIdx.y, b = bh>>3, h = bh&7;
  const int q0 = blockIdx.x*64;
  const int tid = threadIdx.x, lane = tid&63, w = tid>>6;
  f32x4 acc[2] = {};
  int qa = q0 + w*16 + (lane&15); if (qa>199) qa=199;   // A-frag row (clamped rows unused)
  const u16* Prow = P + ((long)bh*200 + qa)*Jpad;
  const int jrow = lane;        // wave stages all 64 j-rows at its d-chunk
  const int d0 = w*8;

  for (int j0=0; j0<Jpad; j0+=64){
    int j = j0 + jrow;
    uint4 vv = make_uint4(0,0,0,0);
    if (j < Lk) vv = *(const uint4*)(KVb + (long)(b*Lk+j)*kv_stride + v_off + d0);
    __syncthreads();   // previous tile fully consumed
    Vt[d0+0][jrow] = (u16)(vv.x&0xffffu); Vt[d0+1][jrow] = (u16)(vv.x>>16);
    Vt[d0+2][jrow] = (u16)(vv.y&0xffffu); Vt[d0+3][jrow] = (u16)(vv.y>>16);
    Vt[d0+4][jrow] = (u16)(vv.z&0xffffu); Vt[d0+5][jrow] = (u16)(vv.z>>16);
    Vt[d0+6][jrow] = (u16)(vv.w&0xffffu); Vt[d0+7][jrow] = (u16)(vv.w>>16);
    __syncthreads();
    #pragma unroll
    for (int ks=0; ks<2; ks++){
      bf16x8 af = *(const bf16x8*)(Prow + j0 + ks*32 + (lane>>4)*8);
      #pragma unroll
      for (int dd=0; dd<2; dd++){
        bf16x8 bfr = *(const bf16x8*)&Vt[dd*16 + (lane&15)][ks*32 + (lane>>4)*8];
        acc[dd] = __builtin_amdgcn_mfma_f32_16x16x32_bf16(af, bfr, acc[dd], 0,0,0);
      }
    }
  }
  #pragma unroll
  for (int dd=0; dd<2; dd++)
  #pragma unroll
  for (int r=0; r<4; r++){
    int qq = q0 + w*16 + (lane>>4)*4 + r;
    if (qq < 200)
      outp[((long)(b*200+qq))*256 + h*32 + dd*16 + (lane&15)] = f2b(acc[dd][r]);
  }
}

// ---------------------------------------------------------------------------
// Fallback flash attention (non-fullws path only). Bias from biasTq[b][q][j].
// ---------------------------------------------------------------------------
__global__ __launch_bounds__(256) void attn_kernel(
    const u16* Qb, int q_stride,
    const u16* KVb, int kv_stride, int k_off, int v_off, int Lk,
    const float* biasTq,
    int nsplit, int chunk,
    float* opart, float* mlpart, float scale)
{
  __shared__ float Ks[64][36];
  __shared__ float Vs[64][36];
  const int b = blockIdx.z, h = blockIdx.y;
  const int split = blockIdx.x % nsplit;
  const int q0 = (blockIdx.x / nsplit) * 64;
  const int tid = threadIdx.x;
  const int cg = tid & 3, r = tid >> 2;
  const int kbeg = split*chunk;
  int kend = kbeg + chunk; if (kend > Lk) kend = Lk;

  int qr = q0 + r; if (qr > 199) qr = 199;
  float qreg[32];
  {
    const u16* qp = Qb + (long)(b*200+qr)*q_stride + h*32;
    #pragma unroll
    for (int w=0; w<4; w++){
      uint4 u = *(const uint4*)(qp + w*8);
      qreg[w*8+0]=b2f((u16)(u.x&0xffffu))*scale; qreg[w*8+1]=b2f((u16)(u.x>>16))*scale;
      qreg[w*8+2]=b2f((u16)(u.y&0xffffu))*scale; qreg[w*8+3]=b2f((u16)(u.y>>16))*scale;
      qreg[w*8+4]=b2f((u16)(u.z&0xffffu))*scale; qreg[w*8+5]=b2f((u16)(u.z>>16))*scale;
      qreg[w*8+6]=b2f((u16)(u.w&0xffffu))*scale; qreg[w*8+7]=b2f((u16)(u.w>>16))*scale;
    }
  }
  const float* bT = biasTq ? biasTq + ((long)(b*200+qr))*CROSSK_ : nullptr;

  float o32[32];
  #pragma unroll
  for (int i=0;i<32;i++) o32[i]=0.f;
  float mrun = -3e38f, lrun = 0.f;

  const int srow = tid>>2, sc8 = (tid&3)*8;
  for (int j0=kbeg; j0<kend; j0+=64){
    int kr = j0 + srow; if (kr > kend-1) kr = kend-1;
    const long base = (long)(b*Lk + kr)*kv_stride;
    uint4 ku = *(const uint4*)(KVb + base + k_off + sc8);
    uint4 vu = *(const uint4*)(KVb + base + v_off + sc8);
    __syncthreads();
    {
      float4 f0, f1;
      f0.x=b2f((u16)(ku.x&0xffffu)); f0.y=b2f((u16)(ku.x>>16)); f0.z=b2f((u16)(ku.y&0xffffu)); f0.w=b2f((u16)(ku.y>>16));
      f1.x=b2f((u16)(ku.z&0xffffu)); f1.y=b2f((u16)(ku.z>>16)); f1.z=b2f((u16)(ku.w&0xffffu)); f1.w=b2f((u16)(ku.w>>16));
      *(float4*)&Ks[srow][sc8] = f0; *(float4*)&Ks[srow][sc8+4] = f1;
      f0.x=b2f((u16)(vu.x&0xffffu)); f0.y=b2f((u16)(vu.x>>16)); f0.z=b2f((u16)(vu.y&0xffffu)); f0.w=b2f((u16)(vu.y>>16));
      f1.x=b2f((u16)(vu.z&0xffffu)); f1.y=b2f((u16)(vu.z>>16)); f1.z=b2f((u16)(vu.w&0xffffu)); f1.w=b2f((u16)(vu.w>>16));
      *(float4*)&Vs[srow][sc8] = f0; *(float4*)&Vs[srow][sc8+4] = f1;
    }
    __syncthreads();

    float sv[16];
    float mloc = -3e38f;
    #pragma unroll
    for (int jj=0;jj<16;jj++){
      const int c = cg + jj*4;
      const float4* kp = (const float4*)&Ks[c][0];
      float a = 0.f;
      #pragma unroll
      for (int dq=0;dq<8;dq++){
        float4 kv = kp[dq];
        a += qreg[dq*4+0]*kv.x + qreg[dq*4+1]*kv.y + qreg[dq*4+2]*kv.z + qreg[dq*4+3]*kv.w;
      }
      if (bT) a += bT[j0 + c];
      if (j0 + c >= kend) a = -3e38f;
      sv[jj] = a; mloc = fmaxf(mloc, a);
    }
    mloc = fmaxf(mloc, __shfl_xor(mloc,1));
    mloc = fmaxf(mloc, __shfl_xor(mloc,2));
    const float mnew = fmaxf(mrun, mloc);
    const float alpha = __expf(mrun - mnew);
    float lloc = 0.f;
    #pragma unroll
    for (int jj=0;jj<16;jj++){
      float p = (j0 + cg + jj*4 >= kend) ? 0.f : __expf(sv[jj]-mnew);
      sv[jj] = p; lloc += p;
    }
    lloc += __shfl_xor(lloc,1);
    lloc += __shfl_xor(lloc,2);
    lrun = lrun*alpha + lloc;
    #pragma unroll
    for (int i=0;i<32;i++) o32[i] *= alpha;
    #pragma unroll
    for (int jj=0;jj<16;jj++){
      const int c = cg + jj*4;
      const float p = sv[jj];
      const float4* vp = (const float4*)&Vs[c][0];
      #pragma unroll
      for (int dq=0;dq<8;dq++){
        float4 v = vp[dq];
        o32[dq*4+0] += p*v.x; o32[dq*4+1] += p*v.y; o32[dq*4+2] += p*v.z; o32[dq*4+3] += p*v.w;
      }
    }
    mrun = mnew;
  }

  #pragma unroll
  for (int d=0;d<32;d++){
    float v = o32[d];
    v += __shfl_xor(v,1);
    v += __shfl_xor(v,2);
    o32[d] = v;
  }
  if (q0 + r < 200){
    const long pbase = (((long)(b*H_+h)*nsplit + split)*200) + (q0 + r);
    float* op = opart + pbase*32;
    #pragma unroll
    for (int i=0;i<8;i++) op[cg*8+i] = o32[cg*8+i];
    if (cg==0){ mlpart[pbase*2] = mrun; mlpart[pbase*2+1] = lrun; }
  }
}

__global__ __launch_bounds__(256) void attn_combine(const float* opart, const float* mlpart,
    int nsplit, u16* outp)
{
  int row = blockIdx.x;
  int b = row/200, qi = row%200;
  int tid = threadIdx.x;
  int h = tid>>5, d = tid&31;
  const long base = ((long)(b*H_+h)*nsplit)*200 + qi;
  float M = -3e38f;
  for (int s=0;s<nsplit;s++) M = fmaxf(M, mlpart[(base + (long)s*200)*2]);
  float L = 0.f, acc = 0.f;
  for (int s=0;s<nsplit;s++){
    const long ix = base + (long)s*200;
    float w = __expf(mlpart[ix*2] - M);
    L   += mlpart[ix*2+1]*w;
    acc += opart[ix*32 + d]*w;
  }
  outp[(long)row*256 + h*32 + d] = f2b(acc / fmaxf(L, 1e-30f));
}

// ---------------------------------------------------------------------------
extern "C" void kernel_launch(void* const* d_in, const int* in_sizes, int n_in,
                              void* d_out, int out_size, void* d_ws, size_t ws_size,
                              hipStream_t stream)
{
  const float* q        = (const float*)d_in[0];
  const float* q_pos    = (const float*)d_in[1];
  const float* memory   = (const float*)d_in[2];
  const float* cbias    = (const float*)d_in[3];
  const float* align_wq = (const float*)d_in[4];
  const float* align_wm = (const float*)d_in[5];
  const float* gate_w1  = (const float*)d_in[6];
  const float* gate_b1  = (const float*)d_in[7];
  const float* gate_w2  = (const float*)d_in[8];
  const float* gate_b2  = (const float*)d_in[9];
  const float* cross_wq = (const float*)d_in[10];
  const float* cross_wm = (const float*)d_in[11];
  const float* sa_in_w  = (const float*)d_in[12];
  const float* sa_in_b  = (const float*)d_in[13];
  const float* sa_out_w = (const float*)d_in[14];
  const float* sa_out_b = (const float*)d_in[15];
  const float* ca_in_w  = (const float*)d_in[16];
  const float* ca_in_b  = (const float*)d_in[17];
  const float* ca_out_w = (const float*)d_in[18];
  const float* ca_out_b = (const float*)d_in[19];
  const float* ffn_w1   = (const float*)d_in[20];
  const float* ffn_b1   = (const float*)d_in[21];
  const float* ffn_w2   = (const float*)d_in[22];
  const float* ffn_b2   = (const float*)d_in[23];
  const float* n1_g = (const float*)d_in[24];
  const float* n1_b = (const float*)d_in[25];
  const float* n2_g = (const float*)d_in[26];
  const float* n2_b = (const float*)d_in[27];
  const float* n3_g = (const float*)d_in[28];
  const float* n3_b = (const float*)d_in[29];
  float* out = (float*)d_out;   // reference output dtype is fp32

  // ---- workspace layout, fitted to ws_size (deterministic per call) ----
  char* wsb = (char*)d_ws;
  size_t off = 0;
  auto alloc = [&](size_t bytes)->char*{
    char* p = wsb + off; off = (off + bytes + 255) & ~(size_t)255; return p;
  };
  const int NSPLIT = 4;   // KV splits (fallback path)
  u16*    qn_bf   = (u16*)   alloc((size_t)BQ_*D_*2);
  float*  vals96  = (float*) alloc((size_t)BQ_*96*4);
  int*    idx96   = (int*)   alloc((size_t)BQ_*96*4);
  float*  alignedv= (float*) alloc((size_t)BQ_*D_*4);
  u16*    cat_bf  = (u16*)   alloc((size_t)BQ_*512*2);
  u16*    h_bf    = (u16*)   alloc((size_t)BQ_*D_*2);
  float*  gatebuf = (float*) alloc((size_t)BQ_*D_*4);
  float*  qx      = (float*) alloc((size_t)BQ_*D_*4);
  u16*    qx_bf   = (u16*)   alloc((size_t)BQ_*D_*2);
  u16*    qk_bf   = (u16*)   alloc((size_t)BQ_*D_*2);
  u16*    qpos2_bf= (u16*)   alloc((size_t)BQ_*D_*2);
  u16*    qkv_bf  = (u16*)   alloc((size_t)BQ_*768*2);
  u16*    attO_bf = (u16*)   alloc((size_t)BQ_*D_*2);
  float*  q2      = (float*) alloc((size_t)BQ_*D_*4);
  unsigned* imp   = (unsigned*)alloc((size_t)B_*K_*4);
  int*    kidx    = (int*)   alloc((size_t)B_*CROSSK_*4);
  u16*    cq_bf   = (u16*)   alloc((size_t)BQ_*D_*2);
  u16*    f1_bf   = (u16*)   alloc((size_t)BQ_*FF_*2);
  float*  f2buf   = (float*) alloc((size_t)BQ_*D_*4);
  float*  opart   = (float*) alloc((size_t)B_*H_*NSPLIT*200*32*4);  // 6.6 MB (fallback)
  float*  mlpart  = (float*) alloc((size_t)B_*H_*NSPLIT*200*2*4);   // 0.4 MB (fallback)
  float*  biasTq  = (float*) alloc((size_t)B_*Q_*CROSSK_*4);        // 6.6 MB, [b][q][j]
  u16*    wb_alwq = (u16*)   alloc((size_t)D_*D_*2);
  u16*    wb_alwm = (u16*)   alloc((size_t)D_*D_*2);
  u16*    wb_crwq = (u16*)   alloc((size_t)D_*D_*2);
  u16*    wb_crwm = (u16*)   alloc((size_t)D_*D_*2);

  const size_t kv_bytes   = (size_t)B_*CROSSK_*512*2;        // 8.4 MB
  const size_t mn_full    = (size_t)BK_*D_*2;                // 67 MB
  const size_t mn_small   = (size_t)K_*D_*2;                 // 8.4 MB
  const size_t sim_full   = (size_t)BQ_*K_*4;                // 105 MB
  size_t remain = (ws_size > off) ? ws_size - off : 0;
  bool fullws = remain >= mn_full + sim_full + (1u<<20);
  size_t mn_bytes = fullws ? mn_full : (mn_small > kv_bytes ? mn_small : kv_bytes);
  int simRows;
  if (fullws) simRows = BQ_;
  else {
    size_t left = (remain > mn_bytes + (1u<<18)) ? remain - mn_bytes - (1u<<18) : 0;
    long r = (long)(left / ((size_t)K_*4));
    simRows = (int)(r < 8 ? 8 : (r > Q_ ? Q_ : r));
  }
  u16*   mn_bf  = (u16*)  alloc(mn_bytes);
  u16*   kvbuf  = (u16*)  mn_bf;     // alias: mn dead before kvbuf is written
  float* simbuf = (float*)alloc((size_t)simRows*K_*4);
  // attention scratch (fullws only): S fp32 (<=52.4MB) + P bf16 (<=26.2MB) in simbuf
  float* Sbuf = simbuf;
  u16*   Pbuf = (u16*)(simbuf + (size_t)64*200*1024);

  auto gemm = [&](int af32, int bf32,
                  const void* A, long lda, long sA,
                  const void* Bm, long ldb, long sB,
                  int M, int N, int Kd,
                  const float* bias, int act,
                  float* Cf, u16* Cb, long ldc, long sC,
                  unsigned* amax, long sAmax,
                  const int* gather, long sGather, int Z){
    GArgs ga;
    ga.A=A; ga.B=Bm; ga.bias=bias; ga.Cf=Cf; ga.Cb=Cb; ga.amax=amax; ga.gather=gather;
    ga.lda=lda; ga.ldb=ldb; ga.ldc=ldc; ga.sA=sA; ga.sB=sB; ga.sC=sC;
    ga.sAmax=sAmax; ga.sGather=sGather;
    ga.M=M; ga.N=N; ga.K=Kd; ga.act=act;
    dim3 grid(N/64, (M+63)/64, Z);
    if (af32 && bf32)      gemm_bt<1,1><<<grid, 256, 0, stream>>>(ga);
    else if (af32)         gemm_bt<1,0><<<grid, 256, 0, stream>>>(ga);
    else if (bf32)         gemm_bt<0,1><<<grid, 256, 0, stream>>>(ga);
    else                   gemm_bt<0,0><<<grid, 256, 0, stream>>>(ga);
  };
  const float ascale = 0.17677669529663687f;  // 1/sqrt(32)

  // --- one-shot weight conversions (bf16) for the 4 l2norm'd projections ---
  w2b_kernel<<<32,256,0,stream>>>(align_wq, wb_alwq, D_*D_);
  w2b_kernel<<<32,256,0,stream>>>(align_wm, wb_alwm, D_*D_);
  w2b_kernel<<<32,256,0,stream>>>(cross_wq, wb_crwq, D_*D_);
  w2b_kernel<<<32,256,0,stream>>>(cross_wm, wb_crwm, D_*D_);

  // --- align: fused projection+l2norm + sim + top-96 ---
  proj_l2norm<1><<<BQ_/64,256,0,stream>>>(q, 256, wb_alwq, qn_bf, BQ_);
  if (fullws){
    proj_l2norm<1><<<BK_/64,256,0,stream>>>(memory, 256, wb_alwm, mn_bf, BK_);
    gemm(0,0, qn_bf,256,(long)200*256, mn_bf,256,(long)K_*256, 200,K_,256,
         nullptr,0, simbuf,nullptr,K_,(long)200*K_, nullptr,0, nullptr,0, B_);
    topk_kernel<<<BQ_,256,0,stream>>>(simbuf, nullptr, K_, 96, vals96, idx96);
  } else {
    for (int b=0;b<B_;b++){
      proj_l2norm<1><<<K_/64,256,0,stream>>>(memory + (size_t)b*K_*256, 256, wb_alwm, mn_bf, K_);
      for (int q0=0; q0<Q_; q0+=simRows){
        int rows = (Q_ - q0 < simRows) ? (Q_ - q0) : simRows;
        gemm(0,0, qn_bf + ((size_t)b*200+q0)*256,256,0, mn_bf,256,0, rows,K_,256,
             nullptr,0, simbuf,nullptr,K_,0, nullptr,0, nullptr,0, 1);
        topk_kernel<<<rows,256,0,stream>>>(simbuf, nullptr, K_, 96,
             vals96 + ((size_t)b*200+q0)*96, idx96 + ((size_t)b*200+q0)*96);
      }
    }
  }
  align_combine<<<BQ_,256,0,stream>>>(vals96, idx96, memory, alignedv);

  // --- gate MLP ---
  make_cat<<<BQ_,256,0,stream>>>(q, alignedv, cat_bf);
  gemm(0,1, cat_bf,512,0, gate_w1,512,0, BQ_,256,512, gate_b1,1, nullptr,h_bf,256,0, nullptr,0, nullptr,0, 1);
  gemm(0,1, h_bf,256,0, gate_w2,256,0, BQ_,256,256, gate_b2,2, gatebuf,nullptr,256,0, nullptr,0, nullptr,0, 1);
  combine_gate<<<BQ_,256,0,stream>>>(q, q_pos, alignedv, gatebuf, qx, qx_bf, qk_bf);

  // --- self attention ---
  gemm(0,1, qk_bf,256,0, sa_in_w,256,0, BQ_,512,256, sa_in_b,0, nullptr,qkv_bf,768,0, nullptr,0, nullptr,0, 1);
  gemm(0,1, qx_bf,256,0, sa_in_w+512*256,256,0, BQ_,256,256, sa_in_b+512,0, nullptr,qkv_bf+512,768,0, nullptr,0, nullptr,0, 1);
  if (fullws){
    qk_score<<<dim3(256/64, 4, B_*H_),256,0,stream>>>(qkv_bf,768, qkv_bf,768,256,
        200, 256, nullptr, Sbuf, ascale);
    softmax_p<256><<<B_*H_*200,256,0,stream>>>(Sbuf, Pbuf);
    pv_kernel<<<dim3(4, B_*H_),256,0,stream>>>(Pbuf, 256, qkv_bf,768,512, 200, attO_bf);
  } else {
    attn_kernel<<<dim3(4*NSPLIT,H_,B_),256,0,stream>>>(qkv_bf,768, qkv_bf,768,256,512,200,
        nullptr, NSPLIT,64, opart,mlpart, ascale);
    attn_combine<<<BQ_,256,0,stream>>>(opart, mlpart, NSPLIT, attO_bf);
  }
  gemm(0,1, attO_bf,256,0, sa_out_w,256,0, BQ_,256,256, sa_out_b,0, q2,nullptr,256,0, nullptr,0, nullptr,0, 1);
  add_ln<<<BQ_,256,0,stream>>>(qx, q2, n1_g, n1_b, q_pos, qx, qx_bf, qpos2_bf);

  // --- cross-memory sparsify (importance = max over Q of sim2, then top-1024) ---
  proj_l2norm<0><<<BQ_/64,256,0,stream>>>(qx_bf, 256, wb_crwq, qn_bf, BQ_);
  fill_u32<<<(B_*K_+255)/256,256,0,stream>>>(imp, 0u, B_*K_);
  if (fullws){
    proj_l2norm<1><<<BK_/64,256,0,stream>>>(memory, 256, wb_crwm, mn_bf, BK_);
    gemm(0,0, qn_bf,256,(long)200*256, mn_bf,256,(long)K_*256, 200,K_,256,
         nullptr,0, nullptr,nullptr,0,0, imp,(long)K_, nullptr,0, B_);
  } else {
    for (int b=0;b<B_;b++){
      proj_l2norm<1><<<K_/64,256,0,stream>>>(memory + (size_t)b*K_*256, 256, wb_crwm, mn_bf, K_);
      gemm(0,0, qn_bf + (size_t)b*200*256,256,0, mn_bf,256,0, 200,K_,256,
           nullptr,0, nullptr,nullptr,0,0, imp + (size_t)b*K_,(long)K_, nullptr,0, 1);
    }
  }
  topk_kernel<<<B_,256,0,stream>>>(nullptr, imp, K_, CROSSK_, vals96 /*scratch*/, kidx);

  // --- cross attention (kvbuf aliases mn region; mn is dead now) ---
  bias_gather2<<<dim3(Q_, B_),256,0,stream>>>(cbias, kidx, biasTq);
  gemm(1,1, memory,256,(long)K_*256, ca_in_w+256*256,256,0, CROSSK_,512,256,
       ca_in_b+256,0, nullptr,kvbuf,512,(long)CROSSK_*512, nullptr,0, kidx,(long)CROSSK_, B_);
  gemm(0,1, qpos2_bf,256,0, ca_in_w,256,0, BQ_,256,256, ca_in_b,0, nullptr,cq_bf,256,0, nullptr,0, nullptr,0, 1);
  if (fullws){
    qk_score<<<dim3(CROSSK_/64, 4, B_*H_),256,0,stream>>>(cq_bf,256, kvbuf,512,0,
        CROSSK_, CROSSK_, biasTq, Sbuf, ascale);
    softmax_p<1024><<<B_*H_*200,256,0,stream>>>(Sbuf, Pbuf);
    pv_kernel<<<dim3(4, B_*H_),256,0,stream>>>(Pbuf, CROSSK_, kvbuf,512,256, CROSSK_, attO_bf);
  } else {
    attn_kernel<<<dim3(4*NSPLIT,H_,B_),256,0,stream>>>(cq_bf,256, kvbuf,512,0,256,CROSSK_,
        biasTq, NSPLIT,256, opart,mlpart, ascale);
    attn_combine<<<BQ_,256,0,stream>>>(opart, mlpart, NSPLIT, attO_bf);
  }
  gemm(0,1, attO_bf,256,0, ca_out_w,256,0, BQ_,256,256, ca_out_b,0, q2,nullptr,256,0, nullptr,0, nullptr,0, 1);
  add_ln<<<BQ_,256,0,stream>>>(qx, q2, n2_g, n2_b, nullptr, qx, qx_bf, nullptr);

  // --- FFN + final LN -> d_out (fp32) ---
  gemm(0,1, qx_bf,256,0, ffn_w1,256,0, BQ_,FF_,256, ffn_b1,1, nullptr,f1_bf,FF_,0, nullptr,0, nullptr,0, 1);
  gemm(0,1, f1_bf,FF_,0, ffn_w2,FF_,0, BQ_,256,FF_, ffn_b2,0, f2buf,nullptr,256,0, nullptr,0, nullptr,0, 1);
  add_ln<<<BQ_,256,0,stream>>>(qx, f2buf, n3_g, n3_b, nullptr, out, nullptr, nullptr);

  (void)in_sizes; (void)n_in; (void)out_size;
}

// Round 7
// 874.105 us; speedup vs baseline: 1.0736x; 1.0736x over previous
//
#include <hip/hip_runtime.h>
#include <hip/hip_bf16.h>
#include <math.h>

// Problem constants
#define B_ 8
#define Q_ 200
#define K_ 16384
#define D_ 256
#define H_ 8
#define DH_ 32
#define ALIGNK_ 96
#define CROSSK_ 1024
#define FF_ 1024
#define BQ_ (B_*Q_)     // 1600
#define BK_ (B_*K_)     // 131072

typedef unsigned short u16;
typedef unsigned long long u64;
typedef short bf16x8 __attribute__((ext_vector_type(8)));
typedef float f32x4 __attribute__((ext_vector_type(4)));

__device__ __forceinline__ float b2f(u16 u){ return __uint_as_float(((unsigned)u)<<16); }
__device__ __forceinline__ u16 f2b(float f){
  unsigned x = __float_as_uint(f);
  unsigned r = x + 0x7FFFu + ((x>>16)&1u);   // round-to-nearest-even
  return (u16)(r>>16);
}
__device__ __forceinline__ unsigned p2u(float lo, float hi){
  return (unsigned)f2b(lo) | ((unsigned)f2b(hi)<<16);
}
__device__ __forceinline__ uint4 pk8(float4 a, float4 b){
  return make_uint4(p2u(a.x,a.y), p2u(a.z,a.w), p2u(b.x,b.y), p2u(b.z,b.w));
}
// order-preserving float->uint key (larger float => larger key)
__device__ __forceinline__ unsigned fkey(float f){ unsigned b=__float_as_uint(f); return (b&0x80000000u)? ~b : (b|0x80000000u); }
__device__ __forceinline__ float funkey(unsigned k){ unsigned b=(k&0x80000000u)? (k^0x80000000u) : ~k; return __uint_as_float(b); }
__device__ __forceinline__ float gelu_f(float x){ return 0.5f*x*(1.0f+erff(x*0.70710678118654752f)); }
__device__ __forceinline__ float sigmoid_f(float x){ return 1.0f/(1.0f+__expf(-x)); }

// ---------------------------------------------------------------------------
// General NT GEMM:  C[m,n] = sum_k A[m,k]*B[n,k]  (fp32 acc). A/B each either
// fp32 (converted to bf16 in registers) or bf16. Tile 64x64, BK=64, 4 waves.
// ---------------------------------------------------------------------------
struct GArgs {
  const void* A; const void* B; const float* bias;
  float* Cf; u16* Cb; unsigned* amax;
  const int* gather;
  long lda, ldb, ldc;
  long sA, sB, sC, sAmax, sGather;
  int M, N, K, act;
};

template<int AF32, int BF32>
__global__ __launch_bounds__(256) void gemm_bt(GArgs g)
{
  const int tid = threadIdx.x;
  const int bz = blockIdx.z;
  const int m0 = blockIdx.y*64, n0 = blockIdx.x*64;
  const int lane = tid & 63, wave = tid >> 6;
  const int wr = wave >> 1, wc = wave & 1;
  __shared__ __align__(16) u16 As[64][72];
  __shared__ __align__(16) u16 Bs[64][72];
  f32x4 acc[2][2] = {};

  const int lrow = tid>>2;
  const int lk = (tid&3)*16;
  int ar = m0 + lrow; if (ar > g.M-1) ar = g.M-1;
  if (g.gather) ar = g.gather[(long)bz*g.sGather + ar];
  int br = n0 + lrow; if (br > g.N-1) br = g.N-1;
  long aoff = (long)bz*g.sA + (long)ar*g.lda + lk;
  long boff = (long)bz*g.sB + (long)br*g.ldb + lk;

  const int nk = g.K >> 6;
  for (int kt=0; kt<nk; ++kt){
    uint4 wa0, wa1, wb0, wb1;
    if (AF32){
      const float* p = (const float*)g.A + aoff;
      float4 f0 = *(const float4*)(p+0);
      float4 f1 = *(const float4*)(p+4);
      float4 f2v= *(const float4*)(p+8);
      float4 f3 = *(const float4*)(p+12);
      wa0 = pk8(f0,f1); wa1 = pk8(f2v,f3);
    } else {
      const u16* p = (const u16*)g.A + aoff;
      wa0 = *(const uint4*)p; wa1 = *(const uint4*)(p+8);
    }
    if (BF32){
      const float* p = (const float*)g.B + boff;
      float4 f0 = *(const float4*)(p+0);
      float4 f1 = *(const float4*)(p+4);
      float4 f2v= *(const float4*)(p+8);
      float4 f3 = *(const float4*)(p+12);
      wb0 = pk8(f0,f1); wb1 = pk8(f2v,f3);
    } else {
      const u16* p = (const u16*)g.B + boff;
      wb0 = *(const uint4*)p; wb1 = *(const uint4*)(p+8);
    }
    aoff += 64; boff += 64;
    __syncthreads();
    *(uint4*)&As[lrow][lk]   = wa0; *(uint4*)&As[lrow][lk+8] = wa1;
    *(uint4*)&Bs[lrow][lk]   = wb0; *(uint4*)&Bs[lrow][lk+8] = wb1;
    __syncthreads();
    #pragma unroll
    for (int kk=0; kk<2; ++kk){
      const int ko = kk*32 + (lane>>4)*8;
      bf16x8 af0 = *(const bf16x8*)&As[wr*32      + (lane&15)][ko];
      bf16x8 af1 = *(const bf16x8*)&As[wr*32 + 16 + (lane&15)][ko];
      bf16x8 bf0 = *(const bf16x8*)&Bs[wc*32      + (lane&15)][ko];
      bf16x8 bf1 = *(const bf16x8*)&Bs[wc*32 + 16 + (lane&15)][ko];
      acc[0][0] = __builtin_amdgcn_mfma_f32_16x16x32_bf16(af0, bf0, acc[0][0], 0,0,0);
      acc[0][1] = __builtin_amdgcn_mfma_f32_16x16x32_bf16(af0, bf1, acc[0][1], 0,0,0);
      acc[1][0] = __builtin_amdgcn_mfma_f32_16x16x32_bf16(af1, bf0, acc[1][0], 0,0,0);
      acc[1][1] = __builtin_amdgcn_mfma_f32_16x16x32_bf16(af1, bf1, acc[1][1], 0,0,0);
    }
  }

  if (g.amax){
    #pragma unroll
    for (int j=0;j<2;j++){
      float mx = -3.0e38f;
      #pragma unroll
      for (int i=0;i<2;i++)
        #pragma unroll
        for (int r=0;r<4;r++) mx = fmaxf(mx, acc[i][j][r]);
      mx = fmaxf(mx, __shfl_xor(mx, 16));
      mx = fmaxf(mx, __shfl_xor(mx, 32));
      if ((lane>>4)==0){
        int n = n0 + wc*32 + j*16 + (lane&15);
        if (n < g.N) atomicMax(&g.amax[(long)bz*g.sAmax + n], fkey(mx));
      }
    }
    return;
  }

  #pragma unroll
  for (int i=0;i<2;i++)
  #pragma unroll
  for (int j=0;j<2;j++)
  #pragma unroll
  for (int r=0;r<4;r++){
    int m = m0 + wr*32 + i*16 + (lane>>4)*4 + r;   // C row = quad*4+reg
    int n = n0 + wc*32 + j*16 + (lane&15);          // C col = lane&15
    if (m < g.M && n < g.N){
      float v = acc[i][j][r];
      if (g.bias) v += g.bias[n];
      if (g.act==1) v = gelu_f(v);
      else if (g.act==2) v = sigmoid_f(v);
      long ci = (long)bz*g.sC + (long)m*g.ldc + n;
      if (g.Cf) g.Cf[ci] = v; else g.Cb[ci] = f2b(v);
    }
  }
}

// fp32 -> bf16 weight conversion (one-shot, 256x256 matrices)
__global__ void w2b_kernel(const float* w, u16* wb, int n)
{
  int i = (blockIdx.x*256 + threadIdx.x)*8;
  if (i < n){
    float4 a = *(const float4*)(w+i), b = *(const float4*)(w+i+4);
    *(uint4*)(wb+i) = pk8(a,b);
  }
}

// ---------------------------------------------------------------------------
// Fused projection + row-L2-normalize (v2, occupancy-focused).
// ---------------------------------------------------------------------------
template<int AF32>
__global__ __launch_bounds__(256) void proj_l2norm(
    const void* Ain, long lda, const u16* Wb, u16* outp, int R)
{
  __shared__ __align__(16) u16 As[64][72];
  __shared__ __align__(16) u16 Bs[64][72];
  const int tid = threadIdx.x;
  const int m0 = blockIdx.x*64;
  const int lane = tid & 63, wave = tid >> 6;
  f32x4 acc[4][4] = {};

  const int lrow = tid>>2, lk = (tid&3)*16;
  int ar = m0 + lrow; if (ar > R-1) ar = R-1;

  for (int kt=0; kt<4; ++kt){
    uint4 wa0, wa1;
    if (AF32){
      const float* p = (const float*)Ain + (long)ar*lda + kt*64 + lk;
      wa0 = pk8(*(const float4*)(p+0), *(const float4*)(p+4));
      wa1 = pk8(*(const float4*)(p+8), *(const float4*)(p+12));
    } else {
      const u16* p = (const u16*)Ain + (long)ar*lda + kt*64 + lk;
      wa0 = *(const uint4*)p; wa1 = *(const uint4*)(p+8);
    }
    #pragma unroll
    for (int nc=0; nc<4; ++nc){
      const u16* wp = Wb + (long)(nc*64 + lrow)*256 + kt*64 + lk;
      uint4 wb0 = *(const uint4*)wp;
      uint4 wb1 = *(const uint4*)(wp+8);
      __syncthreads();
      if (nc==0){ *(uint4*)&As[lrow][lk] = wa0; *(uint4*)&As[lrow][lk+8] = wa1; }
      *(uint4*)&Bs[lrow][lk] = wb0; *(uint4*)&Bs[lrow][lk+8] = wb1;
      __syncthreads();
      #pragma unroll
      for (int kk=0; kk<2; ++kk){
        const int ko = kk*32 + (lane>>4)*8;
        bf16x8 af = *(const bf16x8*)&As[wave*16 + (lane&15)][ko];
        #pragma unroll
        for (int j=0; j<4; j++){
          bf16x8 bfr = *(const bf16x8*)&Bs[j*16 + (lane&15)][ko];
          acc[nc][j] = __builtin_amdgcn_mfma_f32_16x16x32_bf16(af, bfr, acc[nc][j], 0,0,0);
        }
      }
    }
  }

  #pragma unroll
  for (int r=0;r<4;r++){
    float ssq = 0.f;
    #pragma unroll
    for (int nc=0;nc<4;nc++)
      #pragma unroll
      for (int j=0;j<4;j++) ssq += acc[nc][j][r]*acc[nc][j][r];
    ssq += __shfl_xor(ssq,1); ssq += __shfl_xor(ssq,2);
    ssq += __shfl_xor(ssq,4); ssq += __shfl_xor(ssq,8);
    float inv = 1.0f/fmaxf(sqrtf(ssq), 1e-6f);
    int row = m0 + wave*16 + (lane>>4)*4 + r;
    if (row < R){
      u16* op = outp + (long)row*256 + (lane&15);
      #pragma unroll
      for (int nc=0;nc<4;nc++)
        #pragma unroll
        for (int j=0;j<4;j++) op[nc*64 + j*16] = f2b(acc[nc][j][r]*inv);
    }
  }
}

// ---------------------------------------------------------------------------
// Exact top-96 of a 16384 fp32 row, two-stage, barrier-light.
// Stage 1: each wave (4096 keys, 64/lane) finds its local 96th VALUE via a
//   32-bit shfl-only descent (no barriers), then appends its >=threshold
//   candidates to LDS as combined keys (fkey<<14)|(16383-idx)  (unique).
//   Soundness: a global top-96 element has <96 greater-valued keys in its
//   own wave, hence survives the wave-local top-96.
// Stage 2: wave 0 runs a 46-bit descent over the <=640 unique combined keys
//   — index tie-break (smallest index wins) is inherent in the key; the
//   final threshold selects EXACTLY 96. Output order arbitrary (set equal
//   to jax.lax.top_k's set; downstream ops are order-invariant).
// ---------------------------------------------------------------------------
#define CAP_ 160
__global__ __launch_bounds__(256) void topk96_kernel(const float* inF,
    float* out_val, int* out_idx)
{
  __shared__ u64 cand[4*CAP_];
  __shared__ int cnum[4];
  __shared__ int poss;
  const int row = blockIdx.x, tid = threadIdx.x;
  const int lane = tid & 63, w = tid >> 6;
  if (tid < 4) cnum[tid] = 0;
  if (tid == 0) poss = 0;

  unsigned kr[64];
  {
    const float4* p = (const float4*)(inF + (long)row*K_);
    #pragma unroll
    for (int jj=0;jj<16;jj++){
      float4 v = p[tid + jj*256];
      kr[jj*4+0]=fkey(v.x); kr[jj*4+1]=fkey(v.y); kr[jj*4+2]=fkey(v.z); kr[jj*4+3]=fkey(v.w);
    }
  }

  // stage 1: wave-local value threshold (no barriers)
  unsigned u = 0;
  for (int bit=31; bit>=0; --bit){
    unsigned cv = u | (1u<<bit);
    int c = 0;
    #pragma unroll
    for (int j=0;j<64;j++) c += (kr[j] >= cv) ? 1 : 0;
    #pragma unroll
    for (int off=32; off; off>>=1) c += __shfl_xor(c, off);
    if (c >= 96){
      u = cv;
      if (c == 96) break;     // wave-uniform decision
    }
  }
  __syncthreads();   // cnum init visible to all waves
  #pragma unroll
  for (int j=0;j<64;j++){
    if (kr[j] >= u){
      int e = (tid<<2) + (j&3) + ((j>>2)<<10);
      int s = atomicAdd(&cnum[w], 1);
      if (s < CAP_) cand[w*CAP_ + s] = ((u64)kr[j] << 14) | (u64)(unsigned)(16383 - e);
    }
  }
  __syncthreads();

  // stage 2: wave 0 selects the global 96 among <=640 unique combined keys
  if (w == 0){
    int n0 = cnum[0]; if (n0 > CAP_) n0 = CAP_;
    int n1 = cnum[1]; if (n1 > CAP_) n1 = CAP_;
    int n2 = cnum[2]; if (n2 > CAP_) n2 = CAP_;
    int n3 = cnum[3]; if (n3 > CAP_) n3 = CAP_;
    const int tot = n0+n1+n2+n3;
    u64 ck[10];
    #pragma unroll
    for (int t=0;t<10;t++){
      int g = lane + t*64;
      u64 v = 0;
      if (g < n0)                 v = cand[g];
      else if (g < n0+n1)         v = cand[CAP_   + g-n0];
      else if (g < n0+n1+n2)      v = cand[2*CAP_ + g-n0-n1];
      else if (g < tot)           v = cand[3*CAP_ + g-n0-n1-n2];
      ck[t] = v;
    }
    u64 U = 0;
    for (int bit=45; bit>=0; --bit){
      u64 cv = U | (1ull<<bit);
      int c = 0;
      #pragma unroll
      for (int t=0;t<10;t++) c += (ck[t] >= cv) ? 1 : 0;
      #pragma unroll
      for (int off=32; off; off>>=1) c += __shfl_xor(c, off);
      if (c >= 96){
        U = cv;
        if (c == 96) break;
      }
    }
    // unique keys => exactly 96 satisfy ck >= U (U >= 1, so zero-padding excluded)
    #pragma unroll
    for (int t=0;t<10;t++){
      if (ck[t] >= U && ck[t] != 0){
        int s = atomicAdd(&poss, 1);
        unsigned kk = (unsigned)(ck[t] >> 14);
        int idx = 16383 - (int)(ck[t] & 0x3FFFull);
        out_val[(long)row*96 + s] = funkey(kk);
        out_idx[(long)row*96 + s] = idx;
      }
    }
  }
}

// ---------------------------------------------------------------------------
// Exact top-RANK of a 16384-long row (bitwise rank-select + tie-break).
// Used for the cross top-1024 (8 rows) and any non-96 case.
// ---------------------------------------------------------------------------
__global__ __launch_bounds__(256) void topk_kernel(const float* inF, const unsigned* inK,
    long in_stride, int RANK, float* out_val, int* out_idx)
{
  __shared__ int red[2][4];
  __shared__ int redt[4];
  __shared__ int poss;
  int row = blockIdx.x, tid = threadIdx.x;
  unsigned kr[64];
  if (inF){
    const float4* p = (const float4*)(inF + (long)row*in_stride);
    #pragma unroll
    for (int jj=0;jj<16;jj++){
      float4 v = p[tid + jj*256];
      kr[jj*4+0]=fkey(v.x); kr[jj*4+1]=fkey(v.y); kr[jj*4+2]=fkey(v.z); kr[jj*4+3]=fkey(v.w);
    }
  } else {
    const uint4* p = (const uint4*)(inK + (long)row*in_stride);
    #pragma unroll
    for (int jj=0;jj<16;jj++){
      uint4 v = p[tid + jj*256];
      kr[jj*4+0]=v.x; kr[jj*4+1]=v.y; kr[jj*4+2]=v.z; kr[jj*4+3]=v.w;
    }
  }
  if (tid==0) poss = 0;

  unsigned u = 0; bool exact = false; int pp = 0;
  for (int bit=31; bit>=0; --bit){
    unsigned cand = u | (1u<<bit);
    int c = 0;
    #pragma unroll
    for (int j=0;j<64;j++) c += (kr[j] >= cand) ? 1 : 0;
    #pragma unroll
    for (int off=32; off; off>>=1) c += __shfl_down(c, off);
    if ((tid&63)==0) red[pp][tid>>6] = c;
    __syncthreads();
    c = red[pp][0]+red[pp][1]+red[pp][2]+red[pp][3];
    pp ^= 1;
    if (c >= RANK){
      u = cand;
      if (c == RANK){ exact = true; break; }
    }
  }

  int t = 0;
  if (!exact){
    int cgt = 0;
    #pragma unroll
    for (int j=0;j<64;j++) cgt += (kr[j] > u) ? 1 : 0;
    #pragma unroll
    for (int off=32; off; off>>=1) cgt += __shfl_down(cgt, off);
    __syncthreads();
    if ((tid&63)==0) redt[tid>>6] = cgt;
    __syncthreads();
    cgt = redt[0]+redt[1]+redt[2]+redt[3];
    int Req = RANK - cgt;   // >=1 always
    for (int bit=13; bit>=0; --bit){
      int cand = t | (1<<bit);
      int c = 0;
      #pragma unroll
      for (int j=0;j<64;j++){
        int e = (tid<<2) + (j&3) + ((j>>2)<<10);
        c += (kr[j]==u && e < cand) ? 1 : 0;
      }
      #pragma unroll
      for (int off=32; off; off>>=1) c += __shfl_down(c, off);
      __syncthreads();
      if ((tid&63)==0) redt[tid>>6] = c;
      __syncthreads();
      c = redt[0]+redt[1]+redt[2]+redt[3];
      if (c < Req) t = cand;
    }
  }
  __syncthreads();
  #pragma unroll
  for (int j=0;j<64;j++){
    int e = (tid<<2) + (j&3) + ((j>>2)<<10);
    unsigned kk = kr[j];
    bool win = exact ? (kk >= u) : (kk > u || (kk == u && e <= t));
    if (win){
      int p2 = atomicAdd(&poss, 1);
      out_val[(long)row*RANK + p2] = funkey(kk);
      out_idx[(long)row*RANK + p2] = e;
    }
  }
}

// ---------------------------------------------------------------------------
// aligned[row,:] = softmax(vals96) . memory[b, idx96, :]   (memory fp32)
// ---------------------------------------------------------------------------
__global__ __launch_bounds__(256) void align_combine(const float* vals, const int* idx,
    const float* memory, float* alignedv)
{
  __shared__ float w[96];
  __shared__ int id[96];
  __shared__ float reds[2];
  int row = blockIdx.x, tid = threadIdx.x;
  int b = row / 200;
  if (tid < 96){ w[tid] = vals[(long)row*96 + tid]; id[tid] = idx[(long)row*96 + tid]; }
  __syncthreads();
  if (tid < 64){
    float a = w[tid];
    float bb2 = (tid < 32) ? w[64+tid] : -3e38f;
    float m = fmaxf(a, bb2);
    #pragma unroll
    for (int off=32; off; off>>=1) m = fmaxf(m, __shfl_xor(m, off));
    if (tid==0) reds[0] = m;
  }
  __syncthreads();
  float m = reds[0];
  if (tid < 96) w[tid] = __expf(w[tid]-m);
  __syncthreads();
  if (tid < 64){
    float a = w[tid] + ((tid<32)? w[64+tid] : 0.f);
    #pragma unroll
    for (int off=32; off; off>>=1) a += __shfl_xor(a, off);
    if (tid==0) reds[1] = a;
  }
  __syncthreads();
  float invs = 1.0f/reds[1];
  float acc = 0.f;
  const float* mb = memory + (long)b*K_*D_;
  for (int k=0;k<96;k++) acc += w[k] * mb[(long)id[k]*D_ + tid];
  alignedv[(long)row*256 + tid] = acc*invs;
}

__global__ void make_cat(const float* q, const float* alignedv, u16* cat)
{
  int row = blockIdx.x, tid = threadIdx.x;
  long i = (long)row*256 + tid;
  cat[(long)row*512 + tid]       = f2b(q[i]);
  cat[(long)row*512 + 256 + tid] = f2b(alignedv[i]);
}

__global__ void combine_gate(const float* q, const float* q_pos, const float* alignedv,
    const float* gate, float* qx, u16* qx_b, u16* qk_b)
{
  int row = blockIdx.x, tid = threadIdx.x;
  long i = (long)row*256 + tid;
  float v = q[i] + gate[i]*alignedv[i];
  qx[i] = v;
  qx_b[i] = f2b(v);
  qk_b[i] = f2b(v + q_pos[i]);
}

// ---------------------------------------------------------------------------
// t = x + y; LN over D=256 (biased var, eps 1e-5). Optional outputs.
// ---------------------------------------------------------------------------
__global__ __launch_bounds__(256) void add_ln(const float* x, const float* y,
    const float* g, const float* bb, const float* q_pos,
    float* out_f, u16* out_b, u16* out_pos_b)
{
  __shared__ float red[8];
  int row = blockIdx.x, tid = threadIdx.x;
  long i = (long)row*256 + tid;
  float t = fminf(fmaxf(x[i] + y[i], -1e6f), 1e6f);
  float s1 = t, s2 = t*t;
  #pragma unroll
  for (int off=32; off; off>>=1){ s1 += __shfl_down(s1,off); s2 += __shfl_down(s2,off); }
  if ((tid&63)==0){ red[(tid>>6)*2] = s1; red[(tid>>6)*2+1] = s2; }
  __syncthreads();
  s1 = red[0]+red[2]+red[4]+red[6];
  s2 = red[1]+red[3]+red[5]+red[7];
  float mu = s1 * (1.0f/256.0f);
  float var = fmaxf(s2 * (1.0f/256.0f) - mu*mu, 0.f);
  float rstd = rsqrtf(var + 1e-5f);
  float v = (t-mu)*rstd*g[tid] + bb[tid];
  if (out_f) out_f[i] = v;
  if (out_b) out_b[i] = f2b(v);
  if (out_pos_b) out_pos_b[i] = f2b(v + q_pos[i]);
}

__global__ void fill_u32(unsigned* p, unsigned val, int n)
{ int i = blockIdx.x*256 + threadIdx.x; if (i<n) p[i] = val; }

// ---------------------------------------------------------------------------
// Dense bias gather, layout [b][q][j]: biasTq[b,q,j] = cbias[b,q,kidx[b,j]].
// ---------------------------------------------------------------------------
__global__ __launch_bounds__(256) void bias_gather2(const float* cbias, const int* kidx,
    float* biasTq)
{
  int qq = blockIdx.x, b = blockIdx.y;
  const float* src = cbias + ((long)b*200+qq)*(long)K_;
  float* dst = biasTq + ((long)b*200+qq)*CROSSK_;
  const int* kp = kidx + b*CROSSK_;
  for (int j=threadIdx.x; j<CROSSK_; j+=256) dst[j] = src[kp[j]];
}

// ---------------------------------------------------------------------------
// MFMA attention, 3-kernel pipeline (fullws path).
// ---------------------------------------------------------------------------
__global__ __launch_bounds__(256) void qk_score(
    const u16* Qb, int q_stride, const u16* KVb, int kv_stride, int k_off,
    int Lk, int Jpad, const float* biasTq, float* S, float scale)
{
  __shared__ __align__(16) u16 Qs[64][40];
  __shared__ __align__(16) u16 Ks[64][40];
  const int bh = blockIdx.z, b = bh>>3, h = bh&7;
  const int q0 = blockIdx.y*64, j0 = blockIdx.x*64;
  const int tid = threadIdx.x, lane = tid&63, w = tid>>6;
  {
    int row = tid>>2, c8 = (tid&3)*8;
    int qr = q0+row; if (qr>199) qr=199;
    *(uint4*)&Qs[row][c8] = *(const uint4*)(Qb + (long)(b*200+qr)*q_stride + h*32 + c8);
    int j = j0+row;
    uint4 kv = make_uint4(0,0,0,0);
    if (j < Lk) kv = *(const uint4*)(KVb + (long)(b*Lk+j)*kv_stride + k_off + c8);
    *(uint4*)&Ks[row][c8] = kv;
  }
  __syncthreads();
  bf16x8 af = *(const bf16x8*)&Qs[w*16 + (lane&15)][(lane>>4)*8];
  f32x4 acc[4];
  #pragma unroll
  for (int jj=0;jj<4;jj++){
    f32x4 zz = {};
    bf16x8 bfr = *(const bf16x8*)&Ks[jj*16 + (lane&15)][(lane>>4)*8];
    acc[jj] = __builtin_amdgcn_mfma_f32_16x16x32_bf16(af, bfr, zz, 0,0,0);
  }
  #pragma unroll
  for (int jj=0;jj<4;jj++)
  #pragma unroll
  for (int r=0;r<4;r++){
    int q = q0 + w*16 + (lane>>4)*4 + r;
    int j = j0 + jj*16 + (lane&15);
    if (q < 200){
      float s = acc[jj][r]*scale;
      if (biasTq) s += biasTq[((long)(b*200+q))*Jpad + j];
      if (j >= Lk) s = -3e38f;
      S[((long)bh*200 + q)*Jpad + j] = s;
    }
  }
}

// Exact row softmax over width JP (compile-time), P written bf16 (normalized).
template<int JP>
__global__ __launch_bounds__(256) void softmax_p(const float* S, u16* P)
{
  __shared__ float red[8];
  const long base = (long)blockIdx.x * JP;
  const int tid = threadIdx.x;
  constexpr int PER = JP/256;
  float v[PER];
  float m = -3e38f;
  #pragma unroll
  for (int i=0;i<PER;i++){ v[i] = S[base + tid + i*256]; m = fmaxf(m, v[i]); }
  #pragma unroll
  for (int off=32; off; off>>=1) m = fmaxf(m, __shfl_xor(m, off));
  if ((tid&63)==0) red[tid>>6] = m;
  __syncthreads();
  m = fmaxf(fmaxf(red[0],red[1]), fmaxf(red[2],red[3]));
  float s = 0.f;
  #pragma unroll
  for (int i=0;i<PER;i++){ v[i] = __expf(v[i]-m); s += v[i]; }
  #pragma unroll
  for (int off=32; off; off>>=1) s += __shfl_xor(s, off);
  if ((tid&63)==0) red[4+(tid>>6)] = s;
  __syncthreads();
  s = red[4]+red[5]+red[6]+red[7];
  float inv = 1.0f/s;   // s >= 1 always
  #pragma unroll
  for (int i=0;i<PER;i++) P[base + tid + i*256] = f2b(v[i]*inv);
}

// O[b,q,h*32+d] = sum_j P[bh,q,j] * V[b,j,d].  V transposed into LDS per tile.
__global__ __launch_bounds__(256) void pv_kernel(
    const u16* P, int Jpad, const u16* KVb, int kv_stride, int v_off, int Lk,
    u16* outp)
{
  __shared__ __align__(16) u16 Vt[32][72];
  const int bh = blockIdx.y, b = bh>>3, h = bh&7;
  const int q0 = blockIdx.x*64;
  const int tid = threadIdx.x, lane = tid&63, w = tid>>6;
  f32x4 acc[2] = {};
  int qa = q0 + w*16 + (lane&15); if (qa>199) qa=199;
  const u16* Prow = P + ((long)bh*200 + qa)*Jpad;
  const int jrow = lane;
  const int d0 = w*8;

  for (int j0=0; j0<Jpad; j0+=64){
    int j = j0 + jrow;
    uint4 vv = make_uint4(0,0,0,0);
    if (j < Lk) vv = *(const uint4*)(KVb + (long)(b*Lk+j)*kv_stride + v_off + d0);
    __syncthreads();
    Vt[d0+0][jrow] = (u16)(vv.x&0xffffu); Vt[d0+1][jrow] = (u16)(vv.x>>16);
    Vt[d0+2][jrow] = (u16)(vv.y&0xffffu); Vt[d0+3][jrow] = (u16)(vv.y>>16);
    Vt[d0+4][jrow] = (u16)(vv.z&0xffffu); Vt[d0+5][jrow] = (u16)(vv.z>>16);
    Vt[d0+6][jrow] = (u16)(vv.w&0xffffu); Vt[d0+7][jrow] = (u16)(vv.w>>16);
    __syncthreads();
    #pragma unroll
    for (int ks=0; ks<2; ks++){
      bf16x8 af = *(const bf16x8*)(Prow + j0 + ks*32 + (lane>>4)*8);
      #pragma unroll
      for (int dd=0; dd<2; dd++){
        bf16x8 bfr = *(const bf16x8*)&Vt[dd*16 + (lane&15)][ks*32 + (lane>>4)*8];
        acc[dd] = __builtin_amdgcn_mfma_f32_16x16x32_bf16(af, bfr, acc[dd], 0,0,0);
      }
    }
  }
  #pragma unroll
  for (int dd=0; dd<2; dd++)
  #pragma unroll
  for (int r=0; r<4; r++){
    int qq = q0 + w*16 + (lane>>4)*4 + r;
    if (qq < 200)
      outp[((long)(b*200+qq))*256 + h*32 + dd*16 + (lane&15)] = f2b(acc[dd][r]);
  }
}

// ---------------------------------------------------------------------------
// Fallback flash attention (non-fullws path only). Bias from biasTq[b][q][j].
// ---------------------------------------------------------------------------
__global__ __launch_bounds__(256) void attn_kernel(
    const u16* Qb, int q_stride,
    const u16* KVb, int kv_stride, int k_off, int v_off, int Lk,
    const float* biasTq,
    int nsplit, int chunk,
    float* opart, float* mlpart, float scale)
{
  __shared__ float Ks[64][36];
  __shared__ float Vs[64][36];
  const int b = blockIdx.z, h = blockIdx.y;
  const int split = blockIdx.x % nsplit;
  const int q0 = (blockIdx.x / nsplit) * 64;
  const int tid = threadIdx.x;
  const int cg = tid & 3, r = tid >> 2;
  const int kbeg = split*chunk;
  int kend = kbeg + chunk; if (kend > Lk) kend = Lk;

  int qr = q0 + r; if (qr > 199) qr = 199;
  float qreg[32];
  {
    const u16* qp = Qb + (long)(b*200+qr)*q_stride + h*32;
    #pragma unroll
    for (int w=0; w<4; w++){
      uint4 u = *(const uint4*)(qp + w*8);
      qreg[w*8+0]=b2f((u16)(u.x&0xffffu))*scale; qreg[w*8+1]=b2f((u16)(u.x>>16))*scale;
      qreg[w*8+2]=b2f((u16)(u.y&0xffffu))*scale; qreg[w*8+3]=b2f((u16)(u.y>>16))*scale;
      qreg[w*8+4]=b2f((u16)(u.z&0xffffu))*scale; qreg[w*8+5]=b2f((u16)(u.z>>16))*scale;
      qreg[w*8+6]=b2f((u16)(u.w&0xffffu))*scale; qreg[w*8+7]=b2f((u16)(u.w>>16))*scale;
    }
  }
  const float* bT = biasTq ? biasTq + ((long)(b*200+qr))*CROSSK_ : nullptr;

  float o32[32];
  #pragma unroll
  for (int i=0;i<32;i++) o32[i]=0.f;
  float mrun = -3e38f, lrun = 0.f;

  const int srow = tid>>2, sc8 = (tid&3)*8;
  for (int j0=kbeg; j0<kend; j0+=64){
    int kr = j0 + srow; if (kr > kend-1) kr = kend-1;
    const long base = (long)(b*Lk + kr)*kv_stride;
    uint4 ku = *(const uint4*)(KVb + base + k_off + sc8);
    uint4 vu = *(const uint4*)(KVb + base + v_off + sc8);
    __syncthreads();
    {
      float4 f0, f1;
      f0.x=b2f((u16)(ku.x&0xffffu)); f0.y=b2f((u16)(ku.x>>16)); f0.z=b2f((u16)(ku.y&0xffffu)); f0.w=b2f((u16)(ku.y>>16));
      f1.x=b2f((u16)(ku.z&0xffffu)); f1.y=b2f((u16)(ku.z>>16)); f1.z=b2f((u16)(ku.w&0xffffu)); f1.w=b2f((u16)(ku.w>>16));
      *(float4*)&Ks[srow][sc8] = f0; *(float4*)&Ks[srow][sc8+4] = f1;
      f0.x=b2f((u16)(vu.x&0xffffu)); f0.y=b2f((u16)(vu.x>>16)); f0.z=b2f((u16)(vu.y&0xffffu)); f0.w=b2f((u16)(vu.y>>16));
      f1.x=b2f((u16)(vu.z&0xffffu)); f1.y=b2f((u16)(vu.z>>16)); f1.z=b2f((u16)(vu.w&0xffffu)); f1.w=b2f((u16)(vu.w>>16));
      *(float4*)&Vs[srow][sc8] = f0; *(float4*)&Vs[srow][sc8+4] = f1;
    }
    __syncthreads();

    float sv[16];
    float mloc = -3e38f;
    #pragma unroll
    for (int jj=0;jj<16;jj++){
      const int c = cg + jj*4;
      const float4* kp = (const float4*)&Ks[c][0];
      float a = 0.f;
      #pragma unroll
      for (int dq=0;dq<8;dq++){
        float4 kv = kp[dq];
        a += qreg[dq*4+0]*kv.x + qreg[dq*4+1]*kv.y + qreg[dq*4+2]*kv.z + qreg[dq*4+3]*kv.w;
      }
      if (bT) a += bT[j0 + c];
      if (j0 + c >= kend) a = -3e38f;
      sv[jj] = a; mloc = fmaxf(mloc, a);
    }
    mloc = fmaxf(mloc, __shfl_xor(mloc,1));
    mloc = fmaxf(mloc, __shfl_xor(mloc,2));
    const float mnew = fmaxf(mrun, mloc);
    const float alpha = __expf(mrun - mnew);
    float lloc = 0.f;
    #pragma unroll
    for (int jj=0;jj<16;jj++){
      float p = (j0 + cg + jj*4 >= kend) ? 0.f : __expf(sv[jj]-mnew);
      sv[jj] = p; lloc += p;
    }
    lloc += __shfl_xor(lloc,1);
    lloc += __shfl_xor(lloc,2);
    lrun = lrun*alpha + lloc;
    #pragma unroll
    for (int i=0;i<32;i++) o32[i] *= alpha;
    #pragma unroll
    for (int jj=0;jj<16;jj++){
      const int c = cg + jj*4;
      const float p = sv[jj];
      const float4* vp = (const float4*)&Vs[c][0];
      #pragma unroll
      for (int dq=0;dq<8;dq++){
        float4 v = vp[dq];
        o32[dq*4+0] += p*v.x; o32[dq*4+1] += p*v.y; o32[dq*4+2] += p*v.z; o32[dq*4+3] += p*v.w;
      }
    }
    mrun = mnew;
  }

  #pragma unroll
  for (int d=0;d<32;d++){
    float v = o32[d];
    v += __shfl_xor(v,1);
    v += __shfl_xor(v,2);
    o32[d] = v;
  }
  if (q0 + r < 200){
    const long pbase = (((long)(b*H_+h)*nsplit + split)*200) + (q0 + r);
    float* op = opart + pbase*32;
    #pragma unroll
    for (int i=0;i<8;i++) op[cg*8+i] = o32[cg*8+i];
    if (cg==0){ mlpart[pbase*2] = mrun; mlpart[pbase*2+1] = lrun; }
  }
}

__global__ __launch_bounds__(256) void attn_combine(const float* opart, const float* mlpart,
    int nsplit, u16* outp)
{
  int row = blockIdx.x;
  int b = row/200, qi = row%200;
  int tid = threadIdx.x;
  int h = tid>>5, d = tid&31;
  const long base = ((long)(b*H_+h)*nsplit)*200 + qi;
  float M = -3e38f;
  for (int s=0;s<nsplit;s++) M = fmaxf(M, mlpart[(base + (long)s*200)*2]);
  float L = 0.f, acc = 0.f;
  for (int s=0;s<nsplit;s++){
    const long ix = base + (long)s*200;
    float w = __expf(mlpart[ix*2] - M);
    L   += mlpart[ix*2+1]*w;
    acc += opart[ix*32 + d]*w;
  }
  outp[(long)row*256 + h*32 + d] = f2b(acc / fmaxf(L, 1e-30f));
}

// ---------------------------------------------------------------------------
extern "C" void kernel_launch(void* const* d_in, const int* in_sizes, int n_in,
                              void* d_out, int out_size, void* d_ws, size_t ws_size,
                              hipStream_t stream)
{
  const float* q        = (const float*)d_in[0];
  const float* q_pos    = (const float*)d_in[1];
  const float* memory   = (const float*)d_in[2];
  const float* cbias    = (const float*)d_in[3];
  const float* align_wq = (const float*)d_in[4];
  const float* align_wm = (const float*)d_in[5];
  const float* gate_w1  = (const float*)d_in[6];
  const float* gate_b1  = (const float*)d_in[7];
  const float* gate_w2  = (const float*)d_in[8];
  const float* gate_b2  = (const float*)d_in[9];
  const float* cross_wq = (const float*)d_in[10];
  const float* cross_wm = (const float*)d_in[11];
  const float* sa_in_w  = (const float*)d_in[12];
  const float* sa_in_b  = (const float*)d_in[13];
  const float* sa_out_w = (const float*)d_in[14];
  const float* sa_out_b = (const float*)d_in[15];
  const float* ca_in_w  = (const float*)d_in[16];
  const float* ca_in_b  = (const float*)d_in[17];
  const float* ca_out_w = (const float*)d_in[18];
  const float* ca_out_b = (const float*)d_in[19];
  const float* ffn_w1   = (const float*)d_in[20];
  const float* ffn_b1   = (const float*)d_in[21];
  const float* ffn_w2   = (const float*)d_in[22];
  const float* ffn_b2   = (const float*)d_in[23];
  const float* n1_g = (const float*)d_in[24];
  const float* n1_b = (const float*)d_in[25];
  const float* n2_g = (const float*)d_in[26];
  const float* n2_b = (const float*)d_in[27];
  const float* n3_g = (const float*)d_in[28];
  const float* n3_b = (const float*)d_in[29];
  float* out = (float*)d_out;   // reference output dtype is fp32

  // ---- workspace layout, fitted to ws_size (deterministic per call) ----
  char* wsb = (char*)d_ws;
  size_t off = 0;
  auto alloc = [&](size_t bytes)->char*{
    char* p = wsb + off; off = (off + bytes + 255) & ~(size_t)255; return p;
  };
  const int NSPLIT = 4;   // KV splits (fallback path)
  u16*    qn_bf   = (u16*)   alloc((size_t)BQ_*D_*2);
  float*  vals96  = (float*) alloc((size_t)BQ_*96*4);
  int*    idx96   = (int*)   alloc((size_t)BQ_*96*4);
  float*  alignedv= (float*) alloc((size_t)BQ_*D_*4);
  u16*    cat_bf  = (u16*)   alloc((size_t)BQ_*512*2);
  u16*    h_bf    = (u16*)   alloc((size_t)BQ_*D_*2);
  float*  gatebuf = (float*) alloc((size_t)BQ_*D_*4);
  float*  qx      = (float*) alloc((size_t)BQ_*D_*4);
  u16*    qx_bf   = (u16*)   alloc((size_t)BQ_*D_*2);
  u16*    qk_bf   = (u16*)   alloc((size_t)BQ_*D_*2);
  u16*    qpos2_bf= (u16*)   alloc((size_t)BQ_*D_*2);
  u16*    qkv_bf  = (u16*)   alloc((size_t)BQ_*768*2);
  u16*    attO_bf = (u16*)   alloc((size_t)BQ_*D_*2);
  float*  q2      = (float*) alloc((size_t)BQ_*D_*4);
  unsigned* imp   = (unsigned*)alloc((size_t)B_*K_*4);
  int*    kidx    = (int*)   alloc((size_t)B_*CROSSK_*4);
  u16*    cq_bf   = (u16*)   alloc((size_t)BQ_*D_*2);
  u16*    f1_bf   = (u16*)   alloc((size_t)BQ_*FF_*2);
  float*  f2buf   = (float*) alloc((size_t)BQ_*D_*4);
  float*  opart   = (float*) alloc((size_t)B_*H_*NSPLIT*200*32*4);  // 6.6 MB (fallback)
  float*  mlpart  = (float*) alloc((size_t)B_*H_*NSPLIT*200*2*4);   // 0.4 MB (fallback)
  float*  biasTq  = (float*) alloc((size_t)B_*Q_*CROSSK_*4);        // 6.6 MB, [b][q][j]
  u16*    wb_alwq = (u16*)   alloc((size_t)D_*D_*2);
  u16*    wb_alwm = (u16*)   alloc((size_t)D_*D_*2);
  u16*    wb_crwq = (u16*)   alloc((size_t)D_*D_*2);
  u16*    wb_crwm = (u16*)   alloc((size_t)D_*D_*2);

  const size_t kv_bytes   = (size_t)B_*CROSSK_*512*2;        // 8.4 MB
  const size_t mn_full    = (size_t)BK_*D_*2;                // 67 MB
  const size_t mn_small   = (size_t)K_*D_*2;                 // 8.4 MB
  const size_t sim_full   = (size_t)BQ_*K_*4;                // 105 MB
  size_t remain = (ws_size > off) ? ws_size - off : 0;
  bool fullws = remain >= mn_full + sim_full + (1u<<20);
  size_t mn_bytes = fullws ? mn_full : (mn_small > kv_bytes ? mn_small : kv_bytes);
  int simRows;
  if (fullws) simRows = BQ_;
  else {
    size_t left = (remain > mn_bytes + (1u<<18)) ? remain - mn_bytes - (1u<<18) : 0;
    long r = (long)(left / ((size_t)K_*4));
    simRows = (int)(r < 8 ? 8 : (r > Q_ ? Q_ : r));
  }
  u16*   mn_bf  = (u16*)  alloc(mn_bytes);
  u16*   kvbuf  = (u16*)  mn_bf;     // alias: mn dead before kvbuf is written
  float* simbuf = (float*)alloc((size_t)simRows*K_*4);
  // attention scratch (fullws only): S fp32 (<=52.4MB) + P bf16 (<=26.2MB) in simbuf
  float* Sbuf = simbuf;
  u16*   Pbuf = (u16*)(simbuf + (size_t)64*200*1024);

  auto gemm = [&](int af32, int bf32,
                  const void* A, long lda, long sA,
                  const void* Bm, long ldb, long sB,
                  int M, int N, int Kd,
                  const float* bias, int act,
                  float* Cf, u16* Cb, long ldc, long sC,
                  unsigned* amax, long sAmax,
                  const int* gather, long sGather, int Z){
    GArgs ga;
    ga.A=A; ga.B=Bm; ga.bias=bias; ga.Cf=Cf; ga.Cb=Cb; ga.amax=amax; ga.gather=gather;
    ga.lda=lda; ga.ldb=ldb; ga.ldc=ldc; ga.sA=sA; ga.sB=sB; ga.sC=sC;
    ga.sAmax=sAmax; ga.sGather=sGather;
    ga.M=M; ga.N=N; ga.K=Kd; ga.act=act;
    dim3 grid(N/64, (M+63)/64, Z);
    if (af32 && bf32)      gemm_bt<1,1><<<grid, 256, 0, stream>>>(ga);
    else if (af32)         gemm_bt<1,0><<<grid, 256, 0, stream>>>(ga);
    else if (bf32)         gemm_bt<0,1><<<grid, 256, 0, stream>>>(ga);
    else                   gemm_bt<0,0><<<grid, 256, 0, stream>>>(ga);
  };
  const float ascale = 0.17677669529663687f;  // 1/sqrt(32)

  // --- one-shot weight conversions (bf16) for the 4 l2norm'd projections ---
  w2b_kernel<<<32,256,0,stream>>>(align_wq, wb_alwq, D_*D_);
  w2b_kernel<<<32,256,0,stream>>>(align_wm, wb_alwm, D_*D_);
  w2b_kernel<<<32,256,0,stream>>>(cross_wq, wb_crwq, D_*D_);
  w2b_kernel<<<32,256,0,stream>>>(cross_wm, wb_crwm, D_*D_);

  // --- align: fused projection+l2norm + sim + top-96 ---
  proj_l2norm<1><<<BQ_/64,256,0,stream>>>(q, 256, wb_alwq, qn_bf, BQ_);
  if (fullws){
    proj_l2norm<1><<<BK_/64,256,0,stream>>>(memory, 256, wb_alwm, mn_bf, BK_);
    gemm(0,0, qn_bf,256,(long)200*256, mn_bf,256,(long)K_*256, 200,K_,256,
         nullptr,0, simbuf,nullptr,K_,(long)200*K_, nullptr,0, nullptr,0, B_);
    topk96_kernel<<<BQ_,256,0,stream>>>(simbuf, vals96, idx96);
  } else {
    for (int b=0;b<B_;b++){
      proj_l2norm<1><<<K_/64,256,0,stream>>>(memory + (size_t)b*K_*256, 256, wb_alwm, mn_bf, K_);
      for (int q0=0; q0<Q_; q0+=simRows){
        int rows = (Q_ - q0 < simRows) ? (Q_ - q0) : simRows;
        gemm(0,0, qn_bf + ((size_t)b*200+q0)*256,256,0, mn_bf,256,0, rows,K_,256,
             nullptr,0, simbuf,nullptr,K_,0, nullptr,0, nullptr,0, 1);
        topk96_kernel<<<rows,256,0,stream>>>(simbuf,
             vals96 + ((size_t)b*200+q0)*96, idx96 + ((size_t)b*200+q0)*96);
      }
    }
  }
  align_combine<<<BQ_,256,0,stream>>>(vals96, idx96, memory, alignedv);

  // --- gate MLP ---
  make_cat<<<BQ_,256,0,stream>>>(q, alignedv, cat_bf);
  gemm(0,1, cat_bf,512,0, gate_w1,512,0, BQ_,256,512, gate_b1,1, nullptr,h_bf,256,0, nullptr,0, nullptr,0, 1);
  gemm(0,1, h_bf,256,0, gate_w2,256,0, BQ_,256,256, gate_b2,2, gatebuf,nullptr,256,0, nullptr,0, nullptr,0, 1);
  combine_gate<<<BQ_,256,0,stream>>>(q, q_pos, alignedv, gatebuf, qx, qx_bf, qk_bf);

  // --- self attention ---
  gemm(0,1, qk_bf,256,0, sa_in_w,256,0, BQ_,512,256, sa_in_b,0, nullptr,qkv_bf,768,0, nullptr,0, nullptr,0, 1);
  gemm(0,1, qx_bf,256,0, sa_in_w+512*256,256,0, BQ_,256,256, sa_in_b+512,0, nullptr,qkv_bf+512,768,0, nullptr,0, nullptr,0, 1);
  if (fullws){
    qk_score<<<dim3(256/64, 4, B_*H_),256,0,stream>>>(qkv_bf,768, qkv_bf,768,256,
        200, 256, nullptr, Sbuf, ascale);
    softmax_p<256><<<B_*H_*200,256,0,stream>>>(Sbuf, Pbuf);
    pv_kernel<<<dim3(4, B_*H_),256,0,stream>>>(Pbuf, 256, qkv_bf,768,512, 200, attO_bf);
  } else {
    attn_kernel<<<dim3(4*NSPLIT,H_,B_),256,0,stream>>>(qkv_bf,768, qkv_bf,768,256,512,200,
        nullptr, NSPLIT,64, opart,mlpart, ascale);
    attn_combine<<<BQ_,256,0,stream>>>(opart, mlpart, NSPLIT, attO_bf);
  }
  gemm(0,1, attO_bf,256,0, sa_out_w,256,0, BQ_,256,256, sa_out_b,0, q2,nullptr,256,0, nullptr,0, nullptr,0, 1);
  add_ln<<<BQ_,256,0,stream>>>(qx, q2, n1_g, n1_b, q_pos, qx, qx_bf, qpos2_bf);

  // --- cross-memory sparsify (importance = max over Q of sim2, then top-1024) ---
  proj_l2norm<0><<<BQ_/64,256,0,stream>>>(qx_bf, 256, wb_crwq, qn_bf, BQ_);
  fill_u32<<<(B_*K_+255)/256,256,0,stream>>>(imp, 0u, B_*K_);
  if (fullws){
    proj_l2norm<1><<<BK_/64,256,0,stream>>>(memory, 256, wb_crwm, mn_bf, BK_);
    gemm(0,0, qn_bf,256,(long)200*256, mn_bf,256,(long)K_*256, 200,K_,256,
         nullptr,0, nullptr,nullptr,0,0, imp,(long)K_, nullptr,0, B_);
  } else {
    for (int b=0;b<B_;b++){
      proj_l2norm<1><<<K_/64,256,0,stream>>>(memory + (size_t)b*K_*256, 256, wb_crwm, mn_bf, K_);
      gemm(0,0, qn_bf + (size_t)b*200*256,256,0, mn_bf,256,0, 200,K_,256,
           nullptr,0, nullptr,nullptr,0,0, imp + (size_t)b*K_,(long)K_, nullptr,0, 1);
    }
  }
  topk_kernel<<<B_,256,0,stream>>>(nullptr, imp, K_, CROSSK_, vals96 /*scratch*/, kidx);

  // --- cross attention (kvbuf aliases mn region; mn is dead now) ---
  bias_gather2<<<dim3(Q_, B_),256,0,stream>>>(cbias, kidx, biasTq);
  gemm(1,1, memory,256,(long)K_*256, ca_in_w+256*256,256,0, CROSSK_,512,256,
       ca_in_b+256,0, nullptr,kvbuf,512,(long)CROSSK_*512, nullptr,0, kidx,(long)CROSSK_, B_);
  gemm(0,1, qpos2_bf,256,0, ca_in_w,256,0, BQ_,256,256, ca_in_b,0, nullptr,cq_bf,256,0, nullptr,0, nullptr,0, 1);
  if (fullws){
    qk_score<<<dim3(CROSSK_/64, 4, B_*H_),256,0,stream>>>(cq_bf,256, kvbuf,512,0,
        CROSSK_, CROSSK_, biasTq, Sbuf, ascale);
    softmax_p<1024><<<B_*H_*200,256,0,stream>>>(Sbuf, Pbuf);
    pv_kernel<<<dim3(4, B_*H_),256,0,stream>>>(Pbuf, CROSSK_, kvbuf,512,256, CROSSK_, attO_bf);
  } else {
    attn_kernel<<<dim3(4*NSPLIT,H_,B_),256,0,stream>>>(cq_bf,256, kvbuf,512,0,256,CROSSK_,
        biasTq, NSPLIT,256, opart,mlpart, ascale);
    attn_combine<<<BQ_,256,0,stream>>>(opart, mlpart, NSPLIT, attO_bf);
  }
  gemm(0,1, attO_bf,256,0, ca_out_w,256,0, BQ_,256,256, ca_out_b,0, q2,nullptr,256,0, nullptr,0, nullptr,0, 1);
  add_ln<<<BQ_,256,0,stream>>>(qx, q2, n2_g, n2_b, nullptr, qx, qx_bf, nullptr);

  // --- FFN + final LN -> d_out (fp32) ---
  gemm(0,1, qx_bf,256,0, ffn_w1,256,0, BQ_,FF_,256, ffn_b1,1, nullptr,f1_bf,FF_,0, nullptr,0, nullptr,0, 1);
  gemm(0,1, f1_bf,FF_,0, ffn_w2,FF_,0, BQ_,256,FF_, ffn_b2,0, f2buf,nullptr,256,0, nullptr,0, nullptr,0, 1);
  add_ln<<<BQ_,256,0,stream>>>(qx, f2buf, n3_g, n3_b, nullptr, out, nullptr, nullptr);

  (void)in_sizes; (void)n_in; (void)out_size;
}

// Round 8
// 846.792 us; speedup vs baseline: 1.1083x; 1.0323x over previous
//
#include <hip/hip_runtime.h>
#include <hip/hip_bf16.h>
#include <math.h>

// Problem constants
#define B_ 8
#define Q_ 200
#define K_ 16384
#define D_ 256
#define H_ 8
#define DH_ 32
#define ALIGNK_ 96
#define CROSSK_ 1024
#define FF_ 1024
#define BQ_ (B_*Q_)     // 1600
#define BK_ (B_*K_)     // 131072

typedef unsigned short u16;
typedef unsigned long long u64;
typedef short bf16x8 __attribute__((ext_vector_type(8)));
typedef float f32x4 __attribute__((ext_vector_type(4)));

__device__ __forceinline__ float b2f(u16 u){ return __uint_as_float(((unsigned)u)<<16); }
__device__ __forceinline__ u16 f2b(float f){
  unsigned x = __float_as_uint(f);
  unsigned r = x + 0x7FFFu + ((x>>16)&1u);   // round-to-nearest-even
  return (u16)(r>>16);
}
__device__ __forceinline__ unsigned p2u(float lo, float hi){
  return (unsigned)f2b(lo) | ((unsigned)f2b(hi)<<16);
}
__device__ __forceinline__ uint4 pk8(float4 a, float4 b){
  return make_uint4(p2u(a.x,a.y), p2u(a.z,a.w), p2u(b.x,b.y), p2u(b.z,b.w));
}
// order-preserving float->uint key (larger float => larger key)
__device__ __forceinline__ unsigned fkey(float f){ unsigned b=__float_as_uint(f); return (b&0x80000000u)? ~b : (b|0x80000000u); }
__device__ __forceinline__ float funkey(unsigned k){ unsigned b=(k&0x80000000u)? (k^0x80000000u) : ~k; return __uint_as_float(b); }
__device__ __forceinline__ float gelu_f(float x){ return 0.5f*x*(1.0f+erff(x*0.70710678118654752f)); }
__device__ __forceinline__ float sigmoid_f(float x){ return 1.0f/(1.0f+__expf(-x)); }

// ---------------------------------------------------------------------------
// General NT GEMM:  C[m,n] = sum_k A[m,k]*B[n,k]  (fp32 acc). A/B each either
// fp32 (converted to bf16 in registers) or bf16. Tile 64x64, BK=64, 4 waves.
// ---------------------------------------------------------------------------
struct GArgs {
  const void* A; const void* B; const float* bias;
  float* Cf; u16* Cb; unsigned* amax;
  const int* gather;
  long lda, ldb, ldc;
  long sA, sB, sC, sAmax, sGather;
  int M, N, K, act;
};

template<int AF32, int BF32>
__global__ __launch_bounds__(256) void gemm_bt(GArgs g)
{
  const int tid = threadIdx.x;
  const int bz = blockIdx.z;
  const int m0 = blockIdx.y*64, n0 = blockIdx.x*64;
  const int lane = tid & 63, wave = tid >> 6;
  const int wr = wave >> 1, wc = wave & 1;
  __shared__ __align__(16) u16 As[64][72];
  __shared__ __align__(16) u16 Bs[64][72];
  f32x4 acc[2][2] = {};

  const int lrow = tid>>2;
  const int lk = (tid&3)*16;
  int ar = m0 + lrow; if (ar > g.M-1) ar = g.M-1;
  if (g.gather) ar = g.gather[(long)bz*g.sGather + ar];
  int br = n0 + lrow; if (br > g.N-1) br = g.N-1;
  long aoff = (long)bz*g.sA + (long)ar*g.lda + lk;
  long boff = (long)bz*g.sB + (long)br*g.ldb + lk;

  const int nk = g.K >> 6;
  for (int kt=0; kt<nk; ++kt){
    uint4 wa0, wa1, wb0, wb1;
    if (AF32){
      const float* p = (const float*)g.A + aoff;
      float4 f0 = *(const float4*)(p+0);
      float4 f1 = *(const float4*)(p+4);
      float4 f2v= *(const float4*)(p+8);
      float4 f3 = *(const float4*)(p+12);
      wa0 = pk8(f0,f1); wa1 = pk8(f2v,f3);
    } else {
      const u16* p = (const u16*)g.A + aoff;
      wa0 = *(const uint4*)p; wa1 = *(const uint4*)(p+8);
    }
    if (BF32){
      const float* p = (const float*)g.B + boff;
      float4 f0 = *(const float4*)(p+0);
      float4 f1 = *(const float4*)(p+4);
      float4 f2v= *(const float4*)(p+8);
      float4 f3 = *(const float4*)(p+12);
      wb0 = pk8(f0,f1); wb1 = pk8(f2v,f3);
    } else {
      const u16* p = (const u16*)g.B + boff;
      wb0 = *(const uint4*)p; wb1 = *(const uint4*)(p+8);
    }
    aoff += 64; boff += 64;
    __syncthreads();
    *(uint4*)&As[lrow][lk]   = wa0; *(uint4*)&As[lrow][lk+8] = wa1;
    *(uint4*)&Bs[lrow][lk]   = wb0; *(uint4*)&Bs[lrow][lk+8] = wb1;
    __syncthreads();
    #pragma unroll
    for (int kk=0; kk<2; ++kk){
      const int ko = kk*32 + (lane>>4)*8;
      bf16x8 af0 = *(const bf16x8*)&As[wr*32      + (lane&15)][ko];
      bf16x8 af1 = *(const bf16x8*)&As[wr*32 + 16 + (lane&15)][ko];
      bf16x8 bf0 = *(const bf16x8*)&Bs[wc*32      + (lane&15)][ko];
      bf16x8 bf1 = *(const bf16x8*)&Bs[wc*32 + 16 + (lane&15)][ko];
      acc[0][0] = __builtin_amdgcn_mfma_f32_16x16x32_bf16(af0, bf0, acc[0][0], 0,0,0);
      acc[0][1] = __builtin_amdgcn_mfma_f32_16x16x32_bf16(af0, bf1, acc[0][1], 0,0,0);
      acc[1][0] = __builtin_amdgcn_mfma_f32_16x16x32_bf16(af1, bf0, acc[1][0], 0,0,0);
      acc[1][1] = __builtin_amdgcn_mfma_f32_16x16x32_bf16(af1, bf1, acc[1][1], 0,0,0);
    }
  }

  if (g.amax){
    #pragma unroll
    for (int j=0;j<2;j++){
      float mx = -3.0e38f;
      #pragma unroll
      for (int i=0;i<2;i++)
        #pragma unroll
        for (int r=0;r<4;r++) mx = fmaxf(mx, acc[i][j][r]);
      mx = fmaxf(mx, __shfl_xor(mx, 16));
      mx = fmaxf(mx, __shfl_xor(mx, 32));
      if ((lane>>4)==0){
        int n = n0 + wc*32 + j*16 + (lane&15);
        if (n < g.N) atomicMax(&g.amax[(long)bz*g.sAmax + n], fkey(mx));
      }
    }
    return;
  }

  #pragma unroll
  for (int i=0;i<2;i++)
  #pragma unroll
  for (int j=0;j<2;j++)
  #pragma unroll
  for (int r=0;r<4;r++){
    int m = m0 + wr*32 + i*16 + (lane>>4)*4 + r;   // C row = quad*4+reg
    int n = n0 + wc*32 + j*16 + (lane&15);          // C col = lane&15
    if (m < g.M && n < g.N){
      float v = acc[i][j][r];
      if (g.bias) v += g.bias[n];
      if (g.act==1) v = gelu_f(v);
      else if (g.act==2) v = sigmoid_f(v);
      long ci = (long)bz*g.sC + (long)m*g.ldc + n;
      if (g.Cf) g.Cf[ci] = v; else g.Cb[ci] = f2b(v);
    }
  }
}

// fp32 -> bf16 weight conversion for 4 matrices in one launch (grid.y = which)
struct W2B4 { const float* s0; const float* s1; const float* s2; const float* s3;
              u16* d0; u16* d1; u16* d2; u16* d3; int n; };
__global__ void w2b4_kernel(W2B4 a)
{
  int m = blockIdx.y;
  const float* s = (m==0)?a.s0:(m==1)?a.s1:(m==2)?a.s2:a.s3;
  u16* d = (m==0)?a.d0:(m==1)?a.d1:(m==2)?a.d2:a.d3;
  int i = (blockIdx.x*256 + threadIdx.x)*8;
  if (i < a.n){
    float4 x = *(const float4*)(s+i), y = *(const float4*)(s+i+4);
    *(uint4*)(d+i) = pk8(x,y);
  }
}

// ---------------------------------------------------------------------------
// Fused projection + row-L2-normalize (v2, occupancy-focused).
// ---------------------------------------------------------------------------
template<int AF32>
__global__ __launch_bounds__(256) void proj_l2norm(
    const void* Ain, long lda, const u16* Wb, u16* outp, int R)
{
  __shared__ __align__(16) u16 As[64][72];
  __shared__ __align__(16) u16 Bs[64][72];
  const int tid = threadIdx.x;
  const int m0 = blockIdx.x*64;
  const int lane = tid & 63, wave = tid >> 6;
  f32x4 acc[4][4] = {};

  const int lrow = tid>>2, lk = (tid&3)*16;
  int ar = m0 + lrow; if (ar > R-1) ar = R-1;

  for (int kt=0; kt<4; ++kt){
    uint4 wa0, wa1;
    if (AF32){
      const float* p = (const float*)Ain + (long)ar*lda + kt*64 + lk;
      wa0 = pk8(*(const float4*)(p+0), *(const float4*)(p+4));
      wa1 = pk8(*(const float4*)(p+8), *(const float4*)(p+12));
    } else {
      const u16* p = (const u16*)Ain + (long)ar*lda + kt*64 + lk;
      wa0 = *(const uint4*)p; wa1 = *(const uint4*)(p+8);
    }
    #pragma unroll
    for (int nc=0; nc<4; ++nc){
      const u16* wp = Wb + (long)(nc*64 + lrow)*256 + kt*64 + lk;
      uint4 wb0 = *(const uint4*)wp;
      uint4 wb1 = *(const uint4*)(wp+8);
      __syncthreads();
      if (nc==0){ *(uint4*)&As[lrow][lk] = wa0; *(uint4*)&As[lrow][lk+8] = wa1; }
      *(uint4*)&Bs[lrow][lk] = wb0; *(uint4*)&Bs[lrow][lk+8] = wb1;
      __syncthreads();
      #pragma unroll
      for (int kk=0; kk<2; ++kk){
        const int ko = kk*32 + (lane>>4)*8;
        bf16x8 af = *(const bf16x8*)&As[wave*16 + (lane&15)][ko];
        #pragma unroll
        for (int j=0; j<4; j++){
          bf16x8 bfr = *(const bf16x8*)&Bs[j*16 + (lane&15)][ko];
          acc[nc][j] = __builtin_amdgcn_mfma_f32_16x16x32_bf16(af, bfr, acc[nc][j], 0,0,0);
        }
      }
    }
  }

  #pragma unroll
  for (int r=0;r<4;r++){
    float ssq = 0.f;
    #pragma unroll
    for (int nc=0;nc<4;nc++)
      #pragma unroll
      for (int j=0;j<4;j++) ssq += acc[nc][j][r]*acc[nc][j][r];
    ssq += __shfl_xor(ssq,1); ssq += __shfl_xor(ssq,2);
    ssq += __shfl_xor(ssq,4); ssq += __shfl_xor(ssq,8);
    float inv = 1.0f/fmaxf(sqrtf(ssq), 1e-6f);
    int row = m0 + wave*16 + (lane>>4)*4 + r;
    if (row < R){
      u16* op = outp + (long)row*256 + (lane&15);
      #pragma unroll
      for (int nc=0;nc<4;nc++)
        #pragma unroll
        for (int j=0;j<4;j++) op[nc*64 + j*16] = f2b(acc[nc][j][r]*inv);
    }
  }
}

// ---------------------------------------------------------------------------
// Exact top-96 of a 16384 fp32 row, two-stage, barrier-light, iteration-lean.
// Stage 1 (per wave, shfl-only): descend bits from 31, maintaining the
//   largest prefix u with count(>=u) >= 96; STOP as soon as the accepted
//   count ccur <= CAP (threshold <= wave 96th value, candidates <= CAP).
// Stage 2 (wave 0): candidates rebased by umin<<14 (+1; 0 = padding) —
//   order-preserving — and the descent starts at msb(max rebased key),
//   skipping the shared high bits. Unique keys => exact 96.
// ---------------------------------------------------------------------------
#define CAP_ 160
__global__ __launch_bounds__(256) void topk96_kernel(const float* inF,
    float* out_val, int* out_idx)
{
  __shared__ u64 cand[4*CAP_];
  __shared__ int cnum[4];
  __shared__ unsigned uws[4];
  __shared__ int poss;
  const int row = blockIdx.x, tid = threadIdx.x;
  const int lane = tid & 63, w = tid >> 6;
  if (tid < 4) cnum[tid] = 0;
  if (tid == 0) poss = 0;

  unsigned kr[64];
  {
    const float4* p = (const float4*)(inF + (long)row*K_);
    #pragma unroll
    for (int jj=0;jj<16;jj++){
      float4 v = p[tid + jj*256];
      kr[jj*4+0]=fkey(v.x); kr[jj*4+1]=fkey(v.y); kr[jj*4+2]=fkey(v.z); kr[jj*4+3]=fkey(v.w);
    }
  }

  // stage 1: wave-local threshold, early-stop at ccur <= CAP_
  unsigned u = 0; int ccur = 4096;
  for (int bit=31; bit>=0; --bit){
    unsigned cv = u | (1u<<bit);
    int c = 0;
    #pragma unroll
    for (int j=0;j<64;j++) c += (kr[j] >= cv) ? 1 : 0;
    #pragma unroll
    for (int off=32; off; off>>=1) c += __shfl_xor(c, off);
    if (c >= 96){ u = cv; ccur = c; }
    if (ccur <= CAP_) break;        // wave-uniform decision
  }
  if (lane == 0) uws[w] = u;
  __syncthreads();   // cnum/uws init visible to all waves
  #pragma unroll
  for (int j=0;j<64;j++){
    if (kr[j] >= u){
      int e = (tid<<2) + (j&3) + ((j>>2)<<10);
      int s = atomicAdd(&cnum[w], 1);
      if (s < CAP_) cand[w*CAP_ + s] = ((u64)kr[j] << 14) | (u64)(unsigned)(16383 - e);
    }
  }
  __syncthreads();

  // stage 2: wave 0 selects the global 96 among <=640 unique combined keys
  if (w == 0){
    int n0 = cnum[0]; if (n0 > CAP_) n0 = CAP_;
    int n1 = cnum[1]; if (n1 > CAP_) n1 = CAP_;
    int n2 = cnum[2]; if (n2 > CAP_) n2 = CAP_;
    int n3 = cnum[3]; if (n3 > CAP_) n3 = CAP_;
    const int tot = n0+n1+n2+n3;
    unsigned umin = uws[0];
    umin = (uws[1] < umin) ? uws[1] : umin;
    umin = (uws[2] < umin) ? uws[2] : umin;
    umin = (uws[3] < umin) ? uws[3] : umin;
    const u64 base = ((u64)umin << 14);
    u64 ck[10];
    #pragma unroll
    for (int t=0;t<10;t++){
      int g = lane + t*64;
      u64 v = 0;
      if (g < n0)                 v = cand[g];
      else if (g < n0+n1)         v = cand[CAP_   + g-n0];
      else if (g < n0+n1+n2)      v = cand[2*CAP_ + g-n0-n1];
      else if (g < tot)           v = cand[3*CAP_ + g-n0-n1-n2];
      ck[t] = v ? (v - base + 1) : 0;   // rebase (order-preserving); 0 = padding
    }
    u64 mx = 0;
    #pragma unroll
    for (int t=0;t<10;t++) mx = (ck[t] > mx) ? ck[t] : mx;
    #pragma unroll
    for (int off=32; off; off>>=1){
      u64 o = (u64)__shfl_xor((long long)mx, off);
      mx = (o > mx) ? o : mx;
    }
    const int topbit = 63 - __clzll(mx | 1);
    u64 U = 0;
    for (int bit=topbit; bit>=0; --bit){
      u64 cv = U | (1ull<<bit);
      int c = 0;
      #pragma unroll
      for (int t=0;t<10;t++) c += (ck[t] >= cv) ? 1 : 0;
      #pragma unroll
      for (int off=32; off; off>>=1) c += __shfl_xor(c, off);
      if (c >= 96){
        U = cv;
        if (c == 96) break;
      }
    }
    // U >= 1 (bit-0 candidate always accepted: tot >= 96) => padding excluded
    #pragma unroll
    for (int t=0;t<10;t++){
      if (ck[t] >= U){
        int s = atomicAdd(&poss, 1);
        u64 orig = ck[t] - 1 + base;
        unsigned kk = (unsigned)(orig >> 14);
        int idx = 16383 - (int)(orig & 0x3FFFull);
        out_val[(long)row*96 + s] = funkey(kk);
        out_idx[(long)row*96 + s] = idx;
      }
    }
  }
}

// ---------------------------------------------------------------------------
// Exact top-RANK of a 16384-long row (bitwise rank-select + tie-break).
// Used for the cross top-1024 (8 rows).
// ---------------------------------------------------------------------------
__global__ __launch_bounds__(256) void topk_kernel(const float* inF, const unsigned* inK,
    long in_stride, int RANK, float* out_val, int* out_idx)
{
  __shared__ int red[2][4];
  __shared__ int redt[4];
  __shared__ int poss;
  int row = blockIdx.x, tid = threadIdx.x;
  unsigned kr[64];
  if (inF){
    const float4* p = (const float4*)(inF + (long)row*in_stride);
    #pragma unroll
    for (int jj=0;jj<16;jj++){
      float4 v = p[tid + jj*256];
      kr[jj*4+0]=fkey(v.x); kr[jj*4+1]=fkey(v.y); kr[jj*4+2]=fkey(v.z); kr[jj*4+3]=fkey(v.w);
    }
  } else {
    const uint4* p = (const uint4*)(inK + (long)row*in_stride);
    #pragma unroll
    for (int jj=0;jj<16;jj++){
      uint4 v = p[tid + jj*256];
      kr[jj*4+0]=v.x; kr[jj*4+1]=v.y; kr[jj*4+2]=v.z; kr[jj*4+3]=v.w;
    }
  }
  if (tid==0) poss = 0;

  unsigned u = 0; bool exact = false; int pp = 0;
  for (int bit=31; bit>=0; --bit){
    unsigned cand = u | (1u<<bit);
    int c = 0;
    #pragma unroll
    for (int j=0;j<64;j++) c += (kr[j] >= cand) ? 1 : 0;
    #pragma unroll
    for (int off=32; off; off>>=1) c += __shfl_down(c, off);
    if ((tid&63)==0) red[pp][tid>>6] = c;
    __syncthreads();
    c = red[pp][0]+red[pp][1]+red[pp][2]+red[pp][3];
    pp ^= 1;
    if (c >= RANK){
      u = cand;
      if (c == RANK){ exact = true; break; }
    }
  }

  int t = 0;
  if (!exact){
    int cgt = 0;
    #pragma unroll
    for (int j=0;j<64;j++) cgt += (kr[j] > u) ? 1 : 0;
    #pragma unroll
    for (int off=32; off; off>>=1) cgt += __shfl_down(cgt, off);
    __syncthreads();
    if ((tid&63)==0) redt[tid>>6] = cgt;
    __syncthreads();
    cgt = redt[0]+redt[1]+redt[2]+redt[3];
    int Req = RANK - cgt;   // >=1 always
    for (int bit=13; bit>=0; --bit){
      int cand = t | (1<<bit);
      int c = 0;
      #pragma unroll
      for (int j=0;j<64;j++){
        int e = (tid<<2) + (j&3) + ((j>>2)<<10);
        c += (kr[j]==u && e < cand) ? 1 : 0;
      }
      #pragma unroll
      for (int off=32; off; off>>=1) c += __shfl_down(c, off);
      __syncthreads();
      if ((tid&63)==0) redt[tid>>6] = c;
      __syncthreads();
      c = redt[0]+redt[1]+redt[2]+redt[3];
      if (c < Req) t = cand;
    }
  }
  __syncthreads();
  #pragma unroll
  for (int j=0;j<64;j++){
    int e = (tid<<2) + (j&3) + ((j>>2)<<10);
    unsigned kk = kr[j];
    bool win = exact ? (kk >= u) : (kk > u || (kk == u && e <= t));
    if (win){
      int p2 = atomicAdd(&poss, 1);
      out_val[(long)row*RANK + p2] = funkey(kk);
      out_idx[(long)row*RANK + p2] = e;
    }
  }
}

// ---------------------------------------------------------------------------
// aligned[row,:] = softmax(vals96) . memory[b, idx96, :]   (memory fp32)
// ---------------------------------------------------------------------------
__global__ __launch_bounds__(256) void align_combine(const float* vals, const int* idx,
    const float* memory, float* alignedv)
{
  __shared__ float w[96];
  __shared__ int id[96];
  __shared__ float reds[2];
  int row = blockIdx.x, tid = threadIdx.x;
  int b = row / 200;
  if (tid < 96){ w[tid] = vals[(long)row*96 + tid]; id[tid] = idx[(long)row*96 + tid]; }
  __syncthreads();
  if (tid < 64){
    float a = w[tid];
    float bb2 = (tid < 32) ? w[64+tid] : -3e38f;
    float m = fmaxf(a, bb2);
    #pragma unroll
    for (int off=32; off; off>>=1) m = fmaxf(m, __shfl_xor(m, off));
    if (tid==0) reds[0] = m;
  }
  __syncthreads();
  float m = reds[0];
  if (tid < 96) w[tid] = __expf(w[tid]-m);
  __syncthreads();
  if (tid < 64){
    float a = w[tid] + ((tid<32)? w[64+tid] : 0.f);
    #pragma unroll
    for (int off=32; off; off>>=1) a += __shfl_xor(a, off);
    if (tid==0) reds[1] = a;
  }
  __syncthreads();
  float invs = 1.0f/reds[1];
  float acc = 0.f;
  const float* mb = memory + (long)b*K_*D_;
  for (int k=0;k<96;k++) acc += w[k] * mb[(long)id[k]*D_ + tid];
  alignedv[(long)row*256 + tid] = acc*invs;
}

__global__ void make_cat(const float* q, const float* alignedv, u16* cat)
{
  int row = blockIdx.x, tid = threadIdx.x;
  long i = (long)row*256 + tid;
  cat[(long)row*512 + tid]       = f2b(q[i]);
  cat[(long)row*512 + 256 + tid] = f2b(alignedv[i]);
}

__global__ void combine_gate(const float* q, const float* q_pos, const float* alignedv,
    const float* gate, float* qx, u16* qx_b, u16* qk_b)
{
  int row = blockIdx.x, tid = threadIdx.x;
  long i = (long)row*256 + tid;
  float v = q[i] + gate[i]*alignedv[i];
  qx[i] = v;
  qx_b[i] = f2b(v);
  qk_b[i] = f2b(v + q_pos[i]);
}

// ---------------------------------------------------------------------------
// t = x + y; LN over D=256 (biased var, eps 1e-5). Optional outputs.
// ---------------------------------------------------------------------------
__global__ __launch_bounds__(256) void add_ln(const float* x, const float* y,
    const float* g, const float* bb, const float* q_pos,
    float* out_f, u16* out_b, u16* out_pos_b)
{
  __shared__ float red[8];
  int row = blockIdx.x, tid = threadIdx.x;
  long i = (long)row*256 + tid;
  float t = fminf(fmaxf(x[i] + y[i], -1e6f), 1e6f);
  float s1 = t, s2 = t*t;
  #pragma unroll
  for (int off=32; off; off>>=1){ s1 += __shfl_down(s1,off); s2 += __shfl_down(s2,off); }
  if ((tid&63)==0){ red[(tid>>6)*2] = s1; red[(tid>>6)*2+1] = s2; }
  __syncthreads();
  s1 = red[0]+red[2]+red[4]+red[6];
  s2 = red[1]+red[3]+red[5]+red[7];
  float mu = s1 * (1.0f/256.0f);
  float var = fmaxf(s2 * (1.0f/256.0f) - mu*mu, 0.f);
  float rstd = rsqrtf(var + 1e-5f);
  float v = (t-mu)*rstd*g[tid] + bb[tid];
  if (out_f) out_f[i] = v;
  if (out_b) out_b[i] = f2b(v);
  if (out_pos_b) out_pos_b[i] = f2b(v + q_pos[i]);
}

__global__ void fill_u32(unsigned* p, unsigned val, int n)
{ int i = blockIdx.x*256 + threadIdx.x; if (i<n) p[i] = val; }

// ---------------------------------------------------------------------------
// Dense bias gather, layout [b][q][j]: biasTq[b,q,j] = cbias[b,q,kidx[b,j]].
// ---------------------------------------------------------------------------
__global__ __launch_bounds__(256) void bias_gather2(const float* cbias, const int* kidx,
    float* biasTq)
{
  int qq = blockIdx.x, b = blockIdx.y;
  const float* src = cbias + ((long)b*200+qq)*(long)K_;
  float* dst = biasTq + ((long)b*200+qq)*CROSSK_;
  const int* kp = kidx + b*CROSSK_;
  for (int j=threadIdx.x; j<CROSSK_; j+=256) dst[j] = src[kp[j]];
}

// ---------------------------------------------------------------------------
// MFMA attention, 3-kernel pipeline (fullws path).
// ---------------------------------------------------------------------------
__global__ __launch_bounds__(256) void qk_score(
    const u16* Qb, int q_stride, const u16* KVb, int kv_stride, int k_off,
    int Lk, int Jpad, const float* biasTq, float* S, float scale)
{
  __shared__ __align__(16) u16 Qs[64][40];
  __shared__ __align__(16) u16 Ks[64][40];
  const int bh = blockIdx.z, b = bh>>3, h = bh&7;
  const int q0 = blockIdx.y*64, j0 = blockIdx.x*64;
  const int tid = threadIdx.x, lane = tid&63, w = tid>>6;
  {
    int row = tid>>2, c8 = (tid&3)*8;
    int qr = q0+row; if (qr>199) qr=199;
    *(uint4*)&Qs[row][c8] = *(const uint4*)(Qb + (long)(b*200+qr)*q_stride + h*32 + c8);
    int j = j0+row;
    uint4 kv = make_uint4(0,0,0,0);
    if (j < Lk) kv = *(const uint4*)(KVb + (long)(b*Lk+j)*kv_stride + k_off + c8);
    *(uint4*)&Ks[row][c8] = kv;
  }
  __syncthreads();
  bf16x8 af = *(const bf16x8*)&Qs[w*16 + (lane&15)][(lane>>4)*8];
  f32x4 acc[4];
  #pragma unroll
  for (int jj=0;jj<4;jj++){
    f32x4 zz = {};
    bf16x8 bfr = *(const bf16x8*)&Ks[jj*16 + (lane&15)][(lane>>4)*8];
    acc[jj] = __builtin_amdgcn_mfma_f32_16x16x32_bf16(af, bfr, zz, 0,0,0);
  }
  #pragma unroll
  for (int jj=0;jj<4;jj++)
  #pragma unroll
  for (int r=0;r<4;r++){
    int q = q0 + w*16 + (lane>>4)*4 + r;
    int j = j0 + jj*16 + (lane&15);
    if (q < 200){
      float s = acc[jj][r]*scale;
      if (biasTq) s += biasTq[((long)(b*200+q))*Jpad + j];
      if (j >= Lk) s = -3e38f;
      S[((long)bh*200 + q)*Jpad + j] = s;
    }
  }
}

// Exact row softmax over width JP (compile-time), P written bf16 (normalized).
template<int JP>
__global__ __launch_bounds__(256) void softmax_p(const float* S, u16* P)
{
  __shared__ float red[8];
  const long base = (long)blockIdx.x * JP;
  const int tid = threadIdx.x;
  constexpr int PER = JP/256;
  float v[PER];
  float m = -3e38f;
  #pragma unroll
  for (int i=0;i<PER;i++){ v[i] = S[base + tid + i*256]; m = fmaxf(m, v[i]); }
  #pragma unroll
  for (int off=32; off; off>>=1) m = fmaxf(m, __shfl_xor(m, off));
  if ((tid&63)==0) red[tid>>6] = m;
  __syncthreads();
  m = fmaxf(fmaxf(red[0],red[1]), fmaxf(red[2],red[3]));
  float s = 0.f;
  #pragma unroll
  for (int i=0;i<PER;i++){ v[i] = __expf(v[i]-m); s += v[i]; }
  #pragma unroll
  for (int off=32; off; off>>=1) s += __shfl_xor(s, off);
  if ((tid&63)==0) red[4+(tid>>6)] = s;
  __syncthreads();
  s = red[4]+red[5]+red[6]+red[7];
  float inv = 1.0f/s;   // s >= 1 always
  #pragma unroll
  for (int i=0;i<PER;i++) P[base + tid + i*256] = f2b(v[i]*inv);
}

// O[b,q,h*32+d] = sum_j P[bh,q,j] * V[b,j,d].  V transposed into LDS per tile.
__global__ __launch_bounds__(256) void pv_kernel(
    const u16* P, int Jpad, const u16* KVb, int kv_stride, int v_off, int Lk,
    u16* outp)
{
  __shared__ __align__(16) u16 Vt[32][72];
  const int bh = blockIdx.y, b = bh>>3, h = bh&7;
  const int q0 = blockIdx.x*64;
  const int tid = threadIdx.x, lane = tid&63, w = tid>>6;
  f32x4 acc[2] = {};
  int qa = q0 + w*16 + (lane&15); if (qa>199) qa=199;
  const u16* Prow = P + ((long)bh*200 + qa)*Jpad;
  const int jrow = lane;
  const int d0 = w*8;

  for (int j0=0; j0<Jpad; j0+=64){
    int j = j0 + jrow;
    uint4 vv = make_uint4(0,0,0,0);
    if (j < Lk) vv = *(const uint4*)(KVb + (long)(b*Lk+j)*kv_stride + v_off + d0);
    __syncthreads();
    Vt[d0+0][jrow] = (u16)(vv.x&0xffffu); Vt[d0+1][jrow] = (u16)(vv.x>>16);
    Vt[d0+2][jrow] = (u16)(vv.y&0xffffu); Vt[d0+3][jrow] = (u16)(vv.y>>16);
    Vt[d0+4][jrow] = (u16)(vv.z&0xffffu); Vt[d0+5][jrow] = (u16)(vv.z>>16);
    Vt[d0+6][jrow] = (u16)(vv.w&0xffffu); Vt[d0+7][jrow] = (u16)(vv.w>>16);
    __syncthreads();
    #pragma unroll
    for (int ks=0; ks<2; ks++){
      bf16x8 af = *(const bf16x8*)(Prow + j0 + ks*32 + (lane>>4)*8);
      #pragma unroll
      for (int dd=0; dd<2; dd++){
        bf16x8 bfr = *(const bf16x8*)&Vt[dd*16 + (lane&15)][ks*32 + (lane>>4)*8];
        acc[dd] = __builtin_amdgcn_mfma_f32_16x16x32_bf16(af, bfr, acc[dd], 0,0,0);
      }
    }
  }
  #pragma unroll
  for (int dd=0; dd<2; dd++)
  #pragma unroll
  for (int r=0; r<4; r++){
    int qq = q0 + w*16 + (lane>>4)*4 + r;
    if (qq < 200)
      outp[((long)(b*200+qq))*256 + h*32 + dd*16 + (lane&15)] = f2b(acc[dd][r]);
  }
}

// ---------------------------------------------------------------------------
// Fallback flash attention (non-fullws path only). Bias from biasTq[b][q][j].
// ---------------------------------------------------------------------------
__global__ __launch_bounds__(256) void attn_kernel(
    const u16* Qb, int q_stride,
    const u16* KVb, int kv_stride, int k_off, int v_off, int Lk,
    const float* biasTq,
    int nsplit, int chunk,
    float* opart, float* mlpart, float scale)
{
  __shared__ float Ks[64][36];
  __shared__ float Vs[64][36];
  const int b = blockIdx.z, h = blockIdx.y;
  const int split = blockIdx.x % nsplit;
  const int q0 = (blockIdx.x / nsplit) * 64;
  const int tid = threadIdx.x;
  const int cg = tid & 3, r = tid >> 2;
  const int kbeg = split*chunk;
  int kend = kbeg + chunk; if (kend > Lk) kend = Lk;

  int qr = q0 + r; if (qr > 199) qr = 199;
  float qreg[32];
  {
    const u16* qp = Qb + (long)(b*200+qr)*q_stride + h*32;
    #pragma unroll
    for (int w=0; w<4; w++){
      uint4 u = *(const uint4*)(qp + w*8);
      qreg[w*8+0]=b2f((u16)(u.x&0xffffu))*scale; qreg[w*8+1]=b2f((u16)(u.x>>16))*scale;
      qreg[w*8+2]=b2f((u16)(u.y&0xffffu))*scale; qreg[w*8+3]=b2f((u16)(u.y>>16))*scale;
      qreg[w*8+4]=b2f((u16)(u.z&0xffffu))*scale; qreg[w*8+5]=b2f((u16)(u.z>>16))*scale;
      qreg[w*8+6]=b2f((u16)(u.w&0xffffu))*scale; qreg[w*8+7]=b2f((u16)(u.w>>16))*scale;
    }
  }
  const float* bT = biasTq ? biasTq + ((long)(b*200+qr))*CROSSK_ : nullptr;

  float o32[32];
  #pragma unroll
  for (int i=0;i<32;i++) o32[i]=0.f;
  float mrun = -3e38f, lrun = 0.f;

  const int srow = tid>>2, sc8 = (tid&3)*8;
  for (int j0=kbeg; j0<kend; j0+=64){
    int kr = j0 + srow; if (kr > kend-1) kr = kend-1;
    const long base = (long)(b*Lk + kr)*kv_stride;
    uint4 ku = *(const uint4*)(KVb + base + k_off + sc8);
    uint4 vu = *(const uint4*)(KVb + base + v_off + sc8);
    __syncthreads();
    {
      float4 f0, f1;
      f0.x=b2f((u16)(ku.x&0xffffu)); f0.y=b2f((u16)(ku.x>>16)); f0.z=b2f((u16)(ku.y&0xffffu)); f0.w=b2f((u16)(ku.y>>16));
      f1.x=b2f((u16)(ku.z&0xffffu)); f1.y=b2f((u16)(ku.z>>16)); f1.z=b2f((u16)(ku.w&0xffffu)); f1.w=b2f((u16)(ku.w>>16));
      *(float4*)&Ks[srow][sc8] = f0; *(float4*)&Ks[srow][sc8+4] = f1;
      f0.x=b2f((u16)(vu.x&0xffffu)); f0.y=b2f((u16)(vu.x>>16)); f0.z=b2f((u16)(vu.y&0xffffu)); f0.w=b2f((u16)(vu.y>>16));
      f1.x=b2f((u16)(vu.z&0xffffu)); f1.y=b2f((u16)(vu.z>>16)); f1.z=b2f((u16)(vu.w&0xffffu)); f1.w=b2f((u16)(vu.w>>16));
      *(float4*)&Vs[srow][sc8] = f0; *(float4*)&Vs[srow][sc8+4] = f1;
    }
    __syncthreads();

    float sv[16];
    float mloc = -3e38f;
    #pragma unroll
    for (int jj=0;jj<16;jj++){
      const int c = cg + jj*4;
      const float4* kp = (const float4*)&Ks[c][0];
      float a = 0.f;
      #pragma unroll
      for (int dq=0;dq<8;dq++){
        float4 kv = kp[dq];
        a += qreg[dq*4+0]*kv.x + qreg[dq*4+1]*kv.y + qreg[dq*4+2]*kv.z + qreg[dq*4+3]*kv.w;
      }
      if (bT) a += bT[j0 + c];
      if (j0 + c >= kend) a = -3e38f;
      sv[jj] = a; mloc = fmaxf(mloc, a);
    }
    mloc = fmaxf(mloc, __shfl_xor(mloc,1));
    mloc = fmaxf(mloc, __shfl_xor(mloc,2));
    const float mnew = fmaxf(mrun, mloc);
    const float alpha = __expf(mrun - mnew);
    float lloc = 0.f;
    #pragma unroll
    for (int jj=0;jj<16;jj++){
      float p = (j0 + cg + jj*4 >= kend) ? 0.f : __expf(sv[jj]-mnew);
      sv[jj] = p; lloc += p;
    }
    lloc += __shfl_xor(lloc,1);
    lloc += __shfl_xor(lloc,2);
    lrun = lrun*alpha + lloc;
    #pragma unroll
    for (int i=0;i<32;i++) o32[i] *= alpha;
    #pragma unroll
    for (int jj=0;jj<16;jj++){
      const int c = cg + jj*4;
      const float p = sv[jj];
      const float4* vp = (const float4*)&Vs[c][0];
      #pragma unroll
      for (int dq=0;dq<8;dq++){
        float4 v = vp[dq];
        o32[dq*4+0] += p*v.x; o32[dq*4+1] += p*v.y; o32[dq*4+2] += p*v.z; o32[dq*4+3] += p*v.w;
      }
    }
    mrun = mnew;
  }

  #pragma unroll
  for (int d=0;d<32;d++){
    float v = o32[d];
    v += __shfl_xor(v,1);
    v += __shfl_xor(v,2);
    o32[d] = v;
  }
  if (q0 + r < 200){
    const long pbase = (((long)(b*H_+h)*nsplit + split)*200) + (q0 + r);
    float* op = opart + pbase*32;
    #pragma unroll
    for (int i=0;i<8;i++) op[cg*8+i] = o32[cg*8+i];
    if (cg==0){ mlpart[pbase*2] = mrun; mlpart[pbase*2+1] = lrun; }
  }
}

__global__ __launch_bounds__(256) void attn_combine(const float* opart, const float* mlpart,
    int nsplit, u16* outp)
{
  int row = blockIdx.x;
  int b = row/200, qi = row%200;
  int tid = threadIdx.x;
  int h = tid>>5, d = tid&31;
  const long base = ((long)(b*H_+h)*nsplit)*200 + qi;
  float M = -3e38f;
  for (int s=0;s<nsplit;s++) M = fmaxf(M, mlpart[(base + (long)s*200)*2]);
  float L = 0.f, acc = 0.f;
  for (int s=0;s<nsplit;s++){
    const long ix = base + (long)s*200;
    float w = __expf(mlpart[ix*2] - M);
    L   += mlpart[ix*2+1]*w;
    acc += opart[ix*32 + d]*w;
  }
  outp[(long)row*256 + h*32 + d] = f2b(acc / fmaxf(L, 1e-30f));
}

// ---------------------------------------------------------------------------
extern "C" void kernel_launch(void* const* d_in, const int* in_sizes, int n_in,
                              void* d_out, int out_size, void* d_ws, size_t ws_size,
                              hipStream_t stream)
{
  const float* q        = (const float*)d_in[0];
  const float* q_pos    = (const float*)d_in[1];
  const float* memory   = (const float*)d_in[2];
  const float* cbias    = (const float*)d_in[3];
  const float* align_wq = (const float*)d_in[4];
  const float* align_wm = (const float*)d_in[5];
  const float* gate_w1  = (const float*)d_in[6];
  const float* gate_b1  = (const float*)d_in[7];
  const float* gate_w2  = (const float*)d_in[8];
  const float* gate_b2  = (const float*)d_in[9];
  const float* cross_wq = (const float*)d_in[10];
  const float* cross_wm = (const float*)d_in[11];
  const float* sa_in_w  = (const float*)d_in[12];
  const float* sa_in_b  = (const float*)d_in[13];
  const float* sa_out_w = (const float*)d_in[14];
  const float* sa_out_b = (const float*)d_in[15];
  const float* ca_in_w  = (const float*)d_in[16];
  const float* ca_in_b  = (const float*)d_in[17];
  const float* ca_out_w = (const float*)d_in[18];
  const float* ca_out_b = (const float*)d_in[19];
  const float* ffn_w1   = (const float*)d_in[20];
  const float* ffn_b1   = (const float*)d_in[21];
  const float* ffn_w2   = (const float*)d_in[22];
  const float* ffn_b2   = (const float*)d_in[23];
  const float* n1_g = (const float*)d_in[24];
  const float* n1_b = (const float*)d_in[25];
  const float* n2_g = (const float*)d_in[26];
  const float* n2_b = (const float*)d_in[27];
  const float* n3_g = (const float*)d_in[28];
  const float* n3_b = (const float*)d_in[29];
  float* out = (float*)d_out;   // reference output dtype is fp32

  // ---- workspace layout, fitted to ws_size (deterministic per call) ----
  char* wsb = (char*)d_ws;
  size_t off = 0;
  auto alloc = [&](size_t bytes)->char*{
    char* p = wsb + off; off = (off + bytes + 255) & ~(size_t)255; return p;
  };
  const int NSPLIT = 4;   // KV splits (fallback path)
  u16*    qn_bf   = (u16*)   alloc((size_t)BQ_*D_*2);
  float*  vals96  = (float*) alloc((size_t)BQ_*96*4);
  int*    idx96   = (int*)   alloc((size_t)BQ_*96*4);
  float*  alignedv= (float*) alloc((size_t)BQ_*D_*4);
  u16*    cat_bf  = (u16*)   alloc((size_t)BQ_*512*2);
  u16*    h_bf    = (u16*)   alloc((size_t)BQ_*D_*2);
  float*  gatebuf = (float*) alloc((size_t)BQ_*D_*4);
  float*  qx      = (float*) alloc((size_t)BQ_*D_*4);
  u16*    qx_bf   = (u16*)   alloc((size_t)BQ_*D_*2);
  u16*    qk_bf   = (u16*)   alloc((size_t)BQ_*D_*2);
  u16*    qpos2_bf= (u16*)   alloc((size_t)BQ_*D_*2);
  u16*    qkv_bf  = (u16*)   alloc((size_t)BQ_*768*2);
  u16*    attO_bf = (u16*)   alloc((size_t)BQ_*D_*2);
  float*  q2      = (float*) alloc((size_t)BQ_*D_*4);
  unsigned* imp   = (unsigned*)alloc((size_t)B_*K_*4);
  int*    kidx    = (int*)   alloc((size_t)B_*CROSSK_*4);
  u16*    cq_bf   = (u16*)   alloc((size_t)BQ_*D_*2);
  u16*    f1_bf   = (u16*)   alloc((size_t)BQ_*FF_*2);
  float*  f2buf   = (float*) alloc((size_t)BQ_*D_*4);
  float*  opart   = (float*) alloc((size_t)B_*H_*NSPLIT*200*32*4);  // 6.6 MB (fallback)
  float*  mlpart  = (float*) alloc((size_t)B_*H_*NSPLIT*200*2*4);   // 0.4 MB (fallback)
  float*  biasTq  = (float*) alloc((size_t)B_*Q_*CROSSK_*4);        // 6.6 MB, [b][q][j]
  u16*    wb_alwq = (u16*)   alloc((size_t)D_*D_*2);
  u16*    wb_alwm = (u16*)   alloc((size_t)D_*D_*2);
  u16*    wb_crwq = (u16*)   alloc((size_t)D_*D_*2);
  u16*    wb_crwm = (u16*)   alloc((size_t)D_*D_*2);

  const size_t kv_bytes   = (size_t)B_*CROSSK_*512*2;        // 8.4 MB
  const size_t mn_full    = (size_t)BK_*D_*2;                // 67 MB
  const size_t mn_small   = (size_t)K_*D_*2;                 // 8.4 MB
  const size_t sim_full   = (size_t)BQ_*K_*4;                // 105 MB
  size_t remain = (ws_size > off) ? ws_size - off : 0;
  bool fullws = remain >= mn_full + sim_full + (1u<<20);
  size_t mn_bytes = fullws ? mn_full : (mn_small > kv_bytes ? mn_small : kv_bytes);
  int simRows;
  if (fullws) simRows = BQ_;
  else {
    size_t left = (remain > mn_bytes + (1u<<18)) ? remain - mn_bytes - (1u<<18) : 0;
    long r = (long)(left / ((size_t)K_*4));
    simRows = (int)(r < 8 ? 8 : (r > Q_ ? Q_ : r));
  }
  u16*   mn_bf  = (u16*)  alloc(mn_bytes);
  u16*   kvbuf  = (u16*)  mn_bf;     // alias: mn dead before kvbuf is written
  float* simbuf = (float*)alloc((size_t)simRows*K_*4);
  // attention scratch (fullws only): S fp32 (<=52.4MB) + P bf16 (<=26.2MB) in simbuf
  float* Sbuf = simbuf;
  u16*   Pbuf = (u16*)(simbuf + (size_t)64*200*1024);

  auto gemm = [&](int af32, int bf32,
                  const void* A, long lda, long sA,
                  const void* Bm, long ldb, long sB,
                  int M, int N, int Kd,
                  const float* bias, int act,
                  float* Cf, u16* Cb, long ldc, long sC,
                  unsigned* amax, long sAmax,
                  const int* gather, long sGather, int Z){
    GArgs ga;
    ga.A=A; ga.B=Bm; ga.bias=bias; ga.Cf=Cf; ga.Cb=Cb; ga.amax=amax; ga.gather=gather;
    ga.lda=lda; ga.ldb=ldb; ga.ldc=ldc; ga.sA=sA; ga.sB=sB; ga.sC=sC;
    ga.sAmax=sAmax; ga.sGather=sGather;
    ga.M=M; ga.N=N; ga.K=Kd; ga.act=act;
    dim3 grid(N/64, (M+63)/64, Z);
    if (af32 && bf32)      gemm_bt<1,1><<<grid, 256, 0, stream>>>(ga);
    else if (af32)         gemm_bt<1,0><<<grid, 256, 0, stream>>>(ga);
    else if (bf32)         gemm_bt<0,1><<<grid, 256, 0, stream>>>(ga);
    else                   gemm_bt<0,0><<<grid, 256, 0, stream>>>(ga);
  };
  const float ascale = 0.17677669529663687f;  // 1/sqrt(32)

  // --- one-shot weight conversions (bf16) for the 4 l2norm'd projections ---
  {
    W2B4 wa; wa.s0=align_wq; wa.s1=align_wm; wa.s2=cross_wq; wa.s3=cross_wm;
    wa.d0=wb_alwq; wa.d1=wb_alwm; wa.d2=wb_crwq; wa.d3=wb_crwm; wa.n=D_*D_;
    w2b4_kernel<<<dim3(32,4),256,0,stream>>>(wa);
  }

  // --- align: fused projection+l2norm + sim + top-96 ---
  proj_l2norm<1><<<BQ_/64,256,0,stream>>>(q, 256, wb_alwq, qn_bf, BQ_);
  if (fullws){
    proj_l2norm<1><<<BK_/64,256,0,stream>>>(memory, 256, wb_alwm, mn_bf, BK_);
    gemm(0,0, qn_bf,256,(long)200*256, mn_bf,256,(long)K_*256, 200,K_,256,
         nullptr,0, simbuf,nullptr,K_,(long)200*K_, nullptr,0, nullptr,0, B_);
    topk96_kernel<<<BQ_,256,0,stream>>>(simbuf, vals96, idx96);
  } else {
    for (int b=0;b<B_;b++){
      proj_l2norm<1><<<K_/64,256,0,stream>>>(memory + (size_t)b*K_*256, 256, wb_alwm, mn_bf, K_);
      for (int q0=0; q0<Q_; q0+=simRows){
        int rows = (Q_ - q0 < simRows) ? (Q_ - q0) : simRows;
        gemm(0,0, qn_bf + ((size_t)b*200+q0)*256,256,0, mn_bf,256,0, rows,K_,256,
             nullptr,0, simbuf,nullptr,K_,0, nullptr,0, nullptr,0, 1);
        topk96_kernel<<<rows,256,0,stream>>>(simbuf,
             vals96 + ((size_t)b*200+q0)*96, idx96 + ((size_t)b*200+q0)*96);
      }
    }
  }
  align_combine<<<BQ_,256,0,stream>>>(vals96, idx96, memory, alignedv);

  // --- gate MLP ---
  make_cat<<<BQ_,256,0,stream>>>(q, alignedv, cat_bf);
  gemm(0,1, cat_bf,512,0, gate_w1,512,0, BQ_,256,512, gate_b1,1, nullptr,h_bf,256,0, nullptr,0, nullptr,0, 1);
  gemm(0,1, h_bf,256,0, gate_w2,256,0, BQ_,256,256, gate_b2,2, gatebuf,nullptr,256,0, nullptr,0, nullptr,0, 1);
  combine_gate<<<BQ_,256,0,stream>>>(q, q_pos, alignedv, gatebuf, qx, qx_bf, qk_bf);

  // --- self attention ---
  gemm(0,1, qk_bf,256,0, sa_in_w,256,0, BQ_,512,256, sa_in_b,0, nullptr,qkv_bf,768,0, nullptr,0, nullptr,0, 1);
  gemm(0,1, qx_bf,256,0, sa_in_w+512*256,256,0, BQ_,256,256, sa_in_b+512,0, nullptr,qkv_bf+512,768,0, nullptr,0, nullptr,0, 1);
  if (fullws){
    qk_score<<<dim3(256/64, 4, B_*H_),256,0,stream>>>(qkv_bf,768, qkv_bf,768,256,
        200, 256, nullptr, Sbuf, ascale);
    softmax_p<256><<<B_*H_*200,256,0,stream>>>(Sbuf, Pbuf);
    pv_kernel<<<dim3(4, B_*H_),256,0,stream>>>(Pbuf, 256, qkv_bf,768,512, 200, attO_bf);
  } else {
    attn_kernel<<<dim3(4*NSPLIT,H_,B_),256,0,stream>>>(qkv_bf,768, qkv_bf,768,256,512,200,
        nullptr, NSPLIT,64, opart,mlpart, ascale);
    attn_combine<<<BQ_,256,0,stream>>>(opart, mlpart, NSPLIT, attO_bf);
  }
  gemm(0,1, attO_bf,256,0, sa_out_w,256,0, BQ_,256,256, sa_out_b,0, q2,nullptr,256,0, nullptr,0, nullptr,0, 1);
  add_ln<<<BQ_,256,0,stream>>>(qx, q2, n1_g, n1_b, q_pos, qx, qx_bf, qpos2_bf);

  // --- cross-memory sparsify (importance = max over Q of sim2, then top-1024) ---
  proj_l2norm<0><<<BQ_/64,256,0,stream>>>(qx_bf, 256, wb_crwq, qn_bf, BQ_);
  fill_u32<<<(B_*K_+255)/256,256,0,stream>>>(imp, 0u, B_*K_);
  if (fullws){
    proj_l2norm<1><<<BK_/64,256,0,stream>>>(memory, 256, wb_crwm, mn_bf, BK_);
    gemm(0,0, qn_bf,256,(long)200*256, mn_bf,256,(long)K_*256, 200,K_,256,
         nullptr,0, nullptr,nullptr,0,0, imp,(long)K_, nullptr,0, B_);
  } else {
    for (int b=0;b<B_;b++){
      proj_l2norm<1><<<K_/64,256,0,stream>>>(memory + (size_t)b*K_*256, 256, wb_crwm, mn_bf, K_);
      gemm(0,0, qn_bf + (size_t)b*200*256,256,0, mn_bf,256,0, 200,K_,256,
           nullptr,0, nullptr,nullptr,0,0, imp + (size_t)b*K_,(long)K_, nullptr,0, 1);
    }
  }
  topk_kernel<<<B_,256,0,stream>>>(nullptr, imp, K_, CROSSK_, vals96 /*scratch*/, kidx);

  // --- cross attention (kvbuf aliases mn region; mn is dead now) ---
  bias_gather2<<<dim3(Q_, B_),256,0,stream>>>(cbias, kidx, biasTq);
  gemm(1,1, memory,256,(long)K_*256, ca_in_w+256*256,256,0, CROSSK_,512,256,
       ca_in_b+256,0, nullptr,kvbuf,512,(long)CROSSK_*512, nullptr,0, kidx,(long)CROSSK_, B_);
  gemm(0,1, qpos2_bf,256,0, ca_in_w,256,0, BQ_,256,256, ca_in_b,0, nullptr,cq_bf,256,0, nullptr,0, nullptr,0, 1);
  if (fullws){
    qk_score<<<dim3(CROSSK_/64, 4, B_*H_),256,0,stream>>>(cq_bf,256, kvbuf,512,0,
        CROSSK_, CROSSK_, biasTq, Sbuf, ascale);
    softmax_p<1024><<<B_*H_*200,256,0,stream>>>(Sbuf, Pbuf);
    pv_kernel<<<dim3(4, B_*H_),256,0,stream>>>(Pbuf, CROSSK_, kvbuf,512,256, CROSSK_, attO_bf);
  } else {
    attn_kernel<<<dim3(4*NSPLIT,H_,B_),256,0,stream>>>(cq_bf,256, kvbuf,512,0,256,CROSSK_,
        biasTq, NSPLIT,256, opart,mlpart, ascale);
    attn_combine<<<BQ_,256,0,stream>>>(opart, mlpart, NSPLIT, attO_bf);
  }
  gemm(0,1, attO_bf,256,0, ca_out_w,256,0, BQ_,256,256, ca_out_b,0, q2,nullptr,256,0, nullptr,0, nullptr,0, 1);
  add_ln<<<BQ_,256,0,stream>>>(qx, q2, n2_g, n2_b, nullptr, qx, qx_bf, nullptr);

  // --- FFN + final LN -> d_out (fp32) ---
  gemm(0,1, qx_bf,256,0, ffn_w1,256,0, BQ_,FF_,256, ffn_b1,1, nullptr,f1_bf,FF_,0, nullptr,0, nullptr,0, 1);
  gemm(0,1, f1_bf,FF_,0, ffn_w2,FF_,0, BQ_,256,FF_, ffn_b2,0, f2buf,nullptr,256,0, nullptr,0, nullptr,0, 1);
  add_ln<<<BQ_,256,0,stream>>>(qx, f2buf, n3_g, n3_b, nullptr, out, nullptr, nullptr);

  (void)in_sizes; (void)n_in; (void)out_size;
}